// Round 1
// baseline (15203.366 us; speedup 1.0000x reference)
//
#include <hip/hip_runtime.h>
#include <math.h>

#define NLAYER 6
#define DMODEL 768
#define NHEAD 12
#define DHEAD 64
#define FFDIM 3072
#define SEQ 512
#define BATCH 8
#define NTOK (BATCH * SEQ) /* 4096 */
#define ND ((size_t)NTOK * DMODEL)

// ---------------------------------------------------------------------------
// GEMM: C = act(A @ W + bias).  A: M x K, W: K x N, C: M x N.
// act: 0 = none, 1 = exact gelu, 2 = scale by 0.125 (q / sqrt(dh))
// Tile: 128x128, BK=8, 256 threads, 8x8 per thread (two 4-wide chunks/dim).
// ---------------------------------------------------------------------------
#define BM 128
#define BN 128
#define BK 8

__global__ __launch_bounds__(256) void gemm_bias(
    const float* __restrict__ A, const float* __restrict__ W,
    const float* __restrict__ bias, float* __restrict__ C,
    int M, int K, int N, int act)
{
    __shared__ float As[BK][BM + 4];
    __shared__ float Bs[BK][BN + 4];

    const int t  = threadIdx.x;
    const int tx = t & 15;
    const int ty = t >> 4;
    const int row0 = blockIdx.y * BM;
    const int col0 = blockIdx.x * BN;

    float acc[8][8];
#pragma unroll
    for (int i = 0; i < 8; ++i)
#pragma unroll
        for (int j = 0; j < 8; ++j) acc[i][j] = 0.f;

    for (int k0 = 0; k0 < K; k0 += BK) {
        // A tile: 128 rows x 8 cols (1024 elems, 4 per thread)
#pragma unroll
        for (int i = 0; i < (BM * BK) / 256; ++i) {
            int idx = t + i * 256;
            int r = idx >> 3;
            int c = idx & 7;
            As[c][r] = A[(size_t)(row0 + r) * K + (k0 + c)];
        }
        // B tile: 8 rows x 128 cols (coalesced)
#pragma unroll
        for (int i = 0; i < (BK * BN) / 256; ++i) {
            int idx = t + i * 256;
            int r = idx >> 7;
            int c = idx & 127;
            Bs[r][c] = W[(size_t)(k0 + r) * N + (col0 + c)];
        }
        __syncthreads();

#pragma unroll
        for (int kk = 0; kk < BK; ++kk) {
            float a[8], b[8];
#pragma unroll
            for (int i = 0; i < 4; ++i) {
                a[i]     = As[kk][ty * 4 + i];
                a[4 + i] = As[kk][64 + ty * 4 + i];
            }
#pragma unroll
            for (int j = 0; j < 4; ++j) {
                b[j]     = Bs[kk][tx * 4 + j];
                b[4 + j] = Bs[kk][64 + tx * 4 + j];
            }
#pragma unroll
            for (int i = 0; i < 8; ++i)
#pragma unroll
                for (int j = 0; j < 8; ++j) acc[i][j] += a[i] * b[j];
        }
        __syncthreads();
    }

#pragma unroll
    for (int i = 0; i < 8; ++i) {
        int r = row0 + ((i < 4) ? (ty * 4 + i) : (64 + ty * 4 + (i - 4)));
#pragma unroll
        for (int j = 0; j < 8; ++j) {
            int c = col0 + ((j < 4) ? (tx * 4 + j) : (64 + tx * 4 + (j - 4)));
            float v = acc[i][j] + bias[c];
            if (act == 1)      v = 0.5f * v * (1.0f + erff(v * 0.70710678118654752f));
            else if (act == 2) v *= 0.125f;
            C[(size_t)r * N + c] = v;
        }
    }
}

// ---------------------------------------------------------------------------
// Attention: one block per (b, h, query-row). q is pre-scaled by 1/8.
// scores (512) in LDS -> softmax -> ctx (64 dims).
// ---------------------------------------------------------------------------
__global__ __launch_bounds__(256) void attn_kernel(
    const float* __restrict__ q, const float* __restrict__ k,
    const float* __restrict__ v, const int* __restrict__ mask,
    float* __restrict__ ctx)
{
    __shared__ float sc[SEQ];
    __shared__ float qs[DHEAD];
    __shared__ float red[8];
    __shared__ float part[4][DHEAD];

    const int idx = blockIdx.x;
    const int qi = idx & (SEQ - 1);
    const int bh = idx >> 9;
    const int h = bh % NHEAD;
    const int b = bh / NHEAD;
    const int t = threadIdx.x;

    const size_t rowq = (size_t)(b * SEQ + qi) * DMODEL + h * DHEAD;
    if (t < DHEAD) qs[t] = q[rowq + t];
    __syncthreads();

    // scores: each thread handles 2 keys, float4 dot over 64 dims
    for (int j = t; j < SEQ; j += 256) {
        const float4* k4 = (const float4*)(k + (size_t)(b * SEQ + j) * DMODEL + h * DHEAD);
        float4 s4 = make_float4(0.f, 0.f, 0.f, 0.f);
#pragma unroll
        for (int d = 0; d < 16; ++d) {
            float4 kv = k4[d];
            s4.x += qs[d * 4 + 0] * kv.x;
            s4.y += qs[d * 4 + 1] * kv.y;
            s4.z += qs[d * 4 + 2] * kv.z;
            s4.w += qs[d * 4 + 3] * kv.w;
        }
        float s = (s4.x + s4.y) + (s4.z + s4.w);
        if (mask[b * SEQ + j] == 0) s = -1e9f;
        sc[j] = s;
    }
    __syncthreads();

    // block max
    float m = -3.4e38f;
    for (int j = t; j < SEQ; j += 256) m = fmaxf(m, sc[j]);
#pragma unroll
    for (int off = 32; off > 0; off >>= 1) m = fmaxf(m, __shfl_down(m, off, 64));
    if ((t & 63) == 0) red[t >> 6] = m;
    __syncthreads();
    const float gmax = fmaxf(fmaxf(red[0], red[1]), fmaxf(red[2], red[3]));

    // exp + block sum
    float ls = 0.f;
    for (int j = t; j < SEQ; j += 256) {
        float e = __expf(sc[j] - gmax);
        sc[j] = e;
        ls += e;
    }
#pragma unroll
    for (int off = 32; off > 0; off >>= 1) ls += __shfl_down(ls, off, 64);
    __syncthreads();  // sc[] writes visible before ctx phase; red[0:3] reads done
    if ((t & 63) == 0) red[4 + (t >> 6)] = ls;
    __syncthreads();
    const float inv = 1.0f / (red[4] + red[5] + red[6] + red[7]);

    // ctx: thread = (d, key-group g of 128); coalesced v reads across d
    const int d = t & 63;
    const int g = t >> 6;
    float acc = 0.f;
    const int j0 = g * 128;
    for (int j = j0; j < j0 + 128; ++j)
        acc += sc[j] * v[(size_t)(b * SEQ + j) * DMODEL + h * DHEAD + d];
    part[g][d] = acc;
    __syncthreads();
    if (t < DHEAD)
        ctx[rowq + d] = (part[0][d] + part[1][d] + part[2][d] + part[3][d]) * inv;
}

// ---------------------------------------------------------------------------
// out = LayerNorm(a + b) * g + beta    (one block per 768-elem row)
// ---------------------------------------------------------------------------
__global__ __launch_bounds__(256) void add_ln_kernel(
    const float* __restrict__ a, const float* __restrict__ b,
    const float* __restrict__ gw, const float* __restrict__ bw,
    float* __restrict__ out)
{
    const int row = blockIdx.x;
    const int t = threadIdx.x;
    __shared__ float red[8];

    const float* ar = a + (size_t)row * DMODEL;
    const float* br = b + (size_t)row * DMODEL;

    float vals[3];
    float s = 0.f;
#pragma unroll
    for (int i = 0; i < 3; ++i) {
        vals[i] = ar[t + i * 256] + br[t + i * 256];
        s += vals[i];
    }
#pragma unroll
    for (int off = 32; off > 0; off >>= 1) s += __shfl_down(s, off, 64);
    if ((t & 63) == 0) red[t >> 6] = s;
    __syncthreads();
    const float mu = (red[0] + red[1] + red[2] + red[3]) * (1.0f / DMODEL);

    float vs = 0.f;
#pragma unroll
    for (int i = 0; i < 3; ++i) {
        float d = vals[i] - mu;
        vs += d * d;
    }
#pragma unroll
    for (int off = 32; off > 0; off >>= 1) vs += __shfl_down(vs, off, 64);
    if ((t & 63) == 0) red[4 + (t >> 6)] = vs;
    __syncthreads();
    const float var = (red[4] + red[5] + red[6] + red[7]) * (1.0f / DMODEL);
    const float inv = rsqrtf(var + 1e-12f);

#pragma unroll
    for (int i = 0; i < 3; ++i) {
        int c = t + i * 256;
        out[(size_t)row * DMODEL + c] = (vals[i] - mu) * inv * gw[c] + bw[c];
    }
}

// ---------------------------------------------------------------------------
extern "C" void kernel_launch(void* const* d_in, const int* in_sizes, int n_in,
                              void* d_out, int out_size, void* d_ws, size_t ws_size,
                              hipStream_t stream)
{
    const float* x    = (const float*)d_in[0];
    const int*   mask = (const int*)d_in[1];
    const float* Wq = (const float*)d_in[2];
    const float* bq = (const float*)d_in[3];
    const float* Wk = (const float*)d_in[4];
    const float* bk = (const float*)d_in[5];
    const float* Wv = (const float*)d_in[6];
    const float* bv = (const float*)d_in[7];
    const float* Wo = (const float*)d_in[8];
    const float* bo = (const float*)d_in[9];
    const float* ln1g = (const float*)d_in[10];
    const float* ln1b = (const float*)d_in[11];
    const float* W1 = (const float*)d_in[12];
    const float* b1 = (const float*)d_in[13];
    const float* W2 = (const float*)d_in[14];
    const float* b2 = (const float*)d_in[15];
    const float* ln2g = (const float*)d_in[16];
    const float* ln2b = (const float*)d_in[17];

    float* ws = (float*)d_ws;
    float* buf0  = ws;             // h (layer input / output)
    float* buf1  = ws + ND;        // q, then sa
    float* buf2  = ws + 2 * ND;    // k, then h2
    float* buf3  = ws + 3 * ND;    // v, then ffn_out
    float* buf4  = ws + 4 * ND;    // ctx
    float* bufFF = ws + 5 * ND;    // N x FF intermediate

    // h = x
    hipMemcpyAsync(buf0, x, ND * sizeof(float), hipMemcpyDeviceToDevice, stream);

    const dim3 gD(DMODEL / BN, NTOK / BM);   // (6, 32)
    const dim3 gFF(FFDIM / BN, NTOK / BM);   // (24, 32)

    for (int l = 0; l < NLAYER; ++l) {
        const float* Wq_l = Wq + (size_t)l * DMODEL * DMODEL;
        const float* Wk_l = Wk + (size_t)l * DMODEL * DMODEL;
        const float* Wv_l = Wv + (size_t)l * DMODEL * DMODEL;
        const float* Wo_l = Wo + (size_t)l * DMODEL * DMODEL;
        const float* W1_l = W1 + (size_t)l * DMODEL * FFDIM;
        const float* W2_l = W2 + (size_t)l * FFDIM * DMODEL;
        const float* bq_l = bq + (size_t)l * DMODEL;
        const float* bk_l = bk + (size_t)l * DMODEL;
        const float* bv_l = bv + (size_t)l * DMODEL;
        const float* bo_l = bo + (size_t)l * DMODEL;
        const float* b1_l = b1 + (size_t)l * FFDIM;
        const float* b2_l = b2 + (size_t)l * DMODEL;

        // q (scaled), k, v projections
        gemm_bias<<<gD, 256, 0, stream>>>(buf0, Wq_l, bq_l, buf1, NTOK, DMODEL, DMODEL, 2);
        gemm_bias<<<gD, 256, 0, stream>>>(buf0, Wk_l, bk_l, buf2, NTOK, DMODEL, DMODEL, 0);
        gemm_bias<<<gD, 256, 0, stream>>>(buf0, Wv_l, bv_l, buf3, NTOK, DMODEL, DMODEL, 0);

        // attention -> ctx
        attn_kernel<<<BATCH * NHEAD * SEQ, 256, 0, stream>>>(buf1, buf2, buf3, mask, buf4);

        // sa = ctx @ Wo + bo
        gemm_bias<<<gD, 256, 0, stream>>>(buf4, Wo_l, bo_l, buf1, NTOK, DMODEL, DMODEL, 0);

        // h2 = LN(sa + h)
        add_ln_kernel<<<NTOK, 256, 0, stream>>>(buf1, buf0, ln1g + (size_t)l * DMODEL,
                                                ln1b + (size_t)l * DMODEL, buf2);

        // ffn
        gemm_bias<<<gFF, 256, 0, stream>>>(buf2, W1_l, b1_l, bufFF, NTOK, DMODEL, FFDIM, 1);
        gemm_bias<<<gD, 256, 0, stream>>>(bufFF, W2_l, b2_l, buf3, NTOK, FFDIM, DMODEL, 0);

        // h = LN(ffn_out + h2)   (last layer writes d_out directly)
        float* hout = (l == NLAYER - 1) ? (float*)d_out : buf0;
        add_ln_kernel<<<NTOK, 256, 0, stream>>>(buf3, buf2, ln2g + (size_t)l * DMODEL,
                                                ln2b + (size_t)l * DMODEL, hout);
    }
}

// Round 2
// 8944.094 us; speedup vs baseline: 1.6998x; 1.6998x over previous
//
#include <hip/hip_runtime.h>
#include <math.h>

#define NLAYER 6
#define DMODEL 768
#define NHEAD 12
#define DHEAD 64
#define FFDIM 3072
#define SEQ 512
#define BATCH 8
#define NTOK (BATCH * SEQ) /* 4096 */
#define ND ((size_t)NTOK * DMODEL)

// ---------------------------------------------------------------------------
// GEMM: C = act(A @ W + bias).  A: M x K, W: K x N, C: M x N.
// act: 0 = none, 1 = exact gelu, 2 = scale by 0.125 (q / sqrt(dh))
// ---------------------------------------------------------------------------
#define BM 128
#define BN 128
#define BK 8

__global__ __launch_bounds__(256) void gemm_bias(
    const float* __restrict__ A, const float* __restrict__ W,
    const float* __restrict__ bias, float* __restrict__ C,
    int M, int K, int N, int act)
{
    __shared__ float As[BK][BM + 4];
    __shared__ float Bs[BK][BN + 4];

    const int t  = threadIdx.x;
    const int tx = t & 15;
    const int ty = t >> 4;
    const int row0 = blockIdx.y * BM;
    const int col0 = blockIdx.x * BN;

    float acc[8][8];
#pragma unroll
    for (int i = 0; i < 8; ++i)
#pragma unroll
        for (int j = 0; j < 8; ++j) acc[i][j] = 0.f;

    for (int k0 = 0; k0 < K; k0 += BK) {
#pragma unroll
        for (int i = 0; i < (BM * BK) / 256; ++i) {
            int idx = t + i * 256;
            int r = idx >> 3;
            int c = idx & 7;
            As[c][r] = A[(size_t)(row0 + r) * K + (k0 + c)];
        }
#pragma unroll
        for (int i = 0; i < (BK * BN) / 256; ++i) {
            int idx = t + i * 256;
            int r = idx >> 7;
            int c = idx & 127;
            Bs[r][c] = W[(size_t)(k0 + r) * N + (col0 + c)];
        }
        __syncthreads();

#pragma unroll
        for (int kk = 0; kk < BK; ++kk) {
            float a[8], b[8];
#pragma unroll
            for (int i = 0; i < 4; ++i) {
                a[i]     = As[kk][ty * 4 + i];
                a[4 + i] = As[kk][64 + ty * 4 + i];
            }
#pragma unroll
            for (int j = 0; j < 4; ++j) {
                b[j]     = Bs[kk][tx * 4 + j];
                b[4 + j] = Bs[kk][64 + tx * 4 + j];
            }
#pragma unroll
            for (int i = 0; i < 8; ++i)
#pragma unroll
                for (int j = 0; j < 8; ++j) acc[i][j] += a[i] * b[j];
        }
        __syncthreads();
    }

#pragma unroll
    for (int i = 0; i < 8; ++i) {
        int r = row0 + ((i < 4) ? (ty * 4 + i) : (64 + ty * 4 + (i - 4)));
#pragma unroll
        for (int j = 0; j < 8; ++j) {
            int c = col0 + ((j < 4) ? (tx * 4 + j) : (64 + tx * 4 + (j - 4)));
            float v = acc[i][j] + bias[c];
            if (act == 1)      v = 0.5f * v * (1.0f + erff(v * 0.70710678118654752f));
            else if (act == 2) v *= 0.125f;
            C[(size_t)r * N + c] = v;
        }
    }
}

// ---------------------------------------------------------------------------
// Flash attention: block = (q-tile of 64, head, batch). 256 threads.
// Thread (rp, c): rp = t>>3 owns q-rows {rp, rp+32}; c = t&7 owns
// keys c*8..c*8+7 (score phase) and out dims c*8..c*8+7 (PV phase).
// K tile is stored with the d-chunk XOR-swizzled by the key-lane bits so
// score-phase reads (row = c*8+jj) spread across banks (row stride 68
// dwords alone puts all c on one bank: 544 % 32 == 0).
// ---------------------------------------------------------------------------
#define QT 64
#define KT 64

__global__ __launch_bounds__(256) void attn_flash(
    const float* __restrict__ q, const float* __restrict__ k,
    const float* __restrict__ v, const int* __restrict__ mask,
    float* __restrict__ ctx)
{
    __shared__ float Ks[KT][68];   // [key][swizzled d]  17408 B
    __shared__ float Vs[KT][68];   // [key][d]           17408 B
    __shared__ float Ps[QT][66];   // [q-row][key]       16896 B
    __shared__ float Ma[KT];       // additive mask

    const int qt = blockIdx.x;
    const int h  = blockIdx.y;
    const int b  = blockIdx.z;
    const int t  = threadIdx.x;
    const int c  = t & 7;
    const int rp = t >> 3;         // 0..31
    const int row0 = rp;
    const int row1 = rp + 32;

    const size_t qbase0 = ((size_t)(b * SEQ + qt * QT + row0)) * DMODEL + h * DHEAD;
    const size_t qbase1 = ((size_t)(b * SEQ + qt * QT + row1)) * DMODEL + h * DHEAD;
    const float4* q0 = (const float4*)(q + qbase0);
    const float4* q1 = (const float4*)(q + qbase1);

    float m0 = -3.4e38f, m1 = -3.4e38f;
    float l0 = 0.f, l1 = 0.f;
    float O0[8], O1[8];
#pragma unroll
    for (int u = 0; u < 8; ++u) { O0[u] = 0.f; O1[u] = 0.f; }

    for (int kt = 0; kt < SEQ / KT; ++kt) {
        // ---- stage K/V tiles (64 rows x 64 d, float4-coalesced) ----
#pragma unroll
        for (int i = 0; i < 4; ++i) {
            int ch = t + i * 256;
            int r  = ch >> 4;
            int d4 = ch & 15;
            size_t g = ((size_t)(b * SEQ + kt * KT + r)) * DMODEL + h * DHEAD + d4 * 4;
            float4 kv = *(const float4*)(k + g);
            float4 vv = *(const float4*)(v + g);
            int kcol = d4 ^ ((r >> 3) & 7);      // swizzle
            *(float4*)&Ks[r][kcol * 4] = kv;
            *(float4*)&Vs[r][d4 * 4]   = vv;
        }
        if (t < KT) Ma[t] = (mask[b * SEQ + kt * KT + t] == 0) ? -1e9f : 0.f;
        __syncthreads();

        // ---- scores: s[row][jj] = q[row] . k[c*8+jj] ----
        float s0[8], s1[8];
#pragma unroll
        for (int jj = 0; jj < 8; ++jj) { s0[jj] = 0.f; s1[jj] = 0.f; }

#pragma unroll
        for (int d4 = 0; d4 < 16; ++d4) {
            float4 qa = q0[d4];          // L1-resident after first tile
            float4 qb = q1[d4];
#pragma unroll
            for (int jj = 0; jj < 8; ++jj) {
                float4 kv = *(const float4*)&Ks[c * 8 + jj][(d4 ^ c) * 4];
                s0[jj] += qa.x * kv.x + qa.y * kv.y + qa.z * kv.z + qa.w * kv.w;
                s1[jj] += qb.x * kv.x + qb.y * kv.y + qb.z * kv.z + qb.w * kv.w;
            }
        }

        // ---- online softmax (rows reduce across the 8 c-lanes) ----
        float tm0 = -3.4e38f, tm1 = -3.4e38f;
#pragma unroll
        for (int jj = 0; jj < 8; ++jj) {
            s0[jj] += Ma[c * 8 + jj];
            s1[jj] += Ma[c * 8 + jj];
            tm0 = fmaxf(tm0, s0[jj]);
            tm1 = fmaxf(tm1, s1[jj]);
        }
#pragma unroll
        for (int off = 1; off < 8; off <<= 1) {
            tm0 = fmaxf(tm0, __shfl_xor(tm0, off));
            tm1 = fmaxf(tm1, __shfl_xor(tm1, off));
        }
        const float mn0 = fmaxf(m0, tm0);
        const float mn1 = fmaxf(m1, tm1);
        const float sc0 = __expf(m0 - mn0);
        const float sc1 = __expf(m1 - mn1);
        float ts0 = 0.f, ts1 = 0.f;
#pragma unroll
        for (int jj = 0; jj < 8; ++jj) {
            float p0 = __expf(s0[jj] - mn0);
            float p1 = __expf(s1[jj] - mn1);
            Ps[row0][c * 8 + jj] = p0;
            Ps[row1][c * 8 + jj] = p1;
            ts0 += p0;
            ts1 += p1;
        }
#pragma unroll
        for (int off = 1; off < 8; off <<= 1) {
            ts0 += __shfl_xor(ts0, off);
            ts1 += __shfl_xor(ts1, off);
        }
        l0 = l0 * sc0 + ts0;
        l1 = l1 * sc1 + ts1;
        m0 = mn0;
        m1 = mn1;
#pragma unroll
        for (int u = 0; u < 8; ++u) { O0[u] *= sc0; O1[u] *= sc1; }
        __syncthreads();   // Ps visible before PV

        // ---- PV: O[row][c*8+u] += P[row][j] * V[j][c*8+u] ----
#pragma unroll 4
        for (int j = 0; j < KT; ++j) {
            float p0 = Ps[row0][j];
            float p1 = Ps[row1][j];
            float4 va = *(const float4*)&Vs[j][c * 8];
            float4 vb = *(const float4*)&Vs[j][c * 8 + 4];
            O0[0] += p0 * va.x; O0[1] += p0 * va.y; O0[2] += p0 * va.z; O0[3] += p0 * va.w;
            O0[4] += p0 * vb.x; O0[5] += p0 * vb.y; O0[6] += p0 * vb.z; O0[7] += p0 * vb.w;
            O1[0] += p1 * va.x; O1[1] += p1 * va.y; O1[2] += p1 * va.z; O1[3] += p1 * va.w;
            O1[4] += p1 * vb.x; O1[5] += p1 * vb.y; O1[6] += p1 * vb.z; O1[7] += p1 * vb.w;
        }
        __syncthreads();   // tile fully consumed before next stage
    }

    const float i0 = 1.f / l0;
    const float i1 = 1.f / l1;
    *(float4*)&ctx[qbase0 + c * 8]     = make_float4(O0[0] * i0, O0[1] * i0, O0[2] * i0, O0[3] * i0);
    *(float4*)&ctx[qbase0 + c * 8 + 4] = make_float4(O0[4] * i0, O0[5] * i0, O0[6] * i0, O0[7] * i0);
    *(float4*)&ctx[qbase1 + c * 8]     = make_float4(O1[0] * i1, O1[1] * i1, O1[2] * i1, O1[3] * i1);
    *(float4*)&ctx[qbase1 + c * 8 + 4] = make_float4(O1[4] * i1, O1[5] * i1, O1[6] * i1, O1[7] * i1);
}

// ---------------------------------------------------------------------------
// out = LayerNorm(a + b) * g + beta    (one block per 768-elem row)
// ---------------------------------------------------------------------------
__global__ __launch_bounds__(256) void add_ln_kernel(
    const float* __restrict__ a, const float* __restrict__ b,
    const float* __restrict__ gw, const float* __restrict__ bw,
    float* __restrict__ out)
{
    const int row = blockIdx.x;
    const int t = threadIdx.x;
    __shared__ float red[8];

    const float* ar = a + (size_t)row * DMODEL;
    const float* br = b + (size_t)row * DMODEL;

    float vals[3];
    float s = 0.f;
#pragma unroll
    for (int i = 0; i < 3; ++i) {
        vals[i] = ar[t + i * 256] + br[t + i * 256];
        s += vals[i];
    }
#pragma unroll
    for (int off = 32; off > 0; off >>= 1) s += __shfl_down(s, off, 64);
    if ((t & 63) == 0) red[t >> 6] = s;
    __syncthreads();
    const float mu = (red[0] + red[1] + red[2] + red[3]) * (1.0f / DMODEL);

    float vs = 0.f;
#pragma unroll
    for (int i = 0; i < 3; ++i) {
        float d = vals[i] - mu;
        vs += d * d;
    }
#pragma unroll
    for (int off = 32; off > 0; off >>= 1) vs += __shfl_down(vs, off, 64);
    if ((t & 63) == 0) red[4 + (t >> 6)] = vs;
    __syncthreads();
    const float var = (red[4] + red[5] + red[6] + red[7]) * (1.0f / DMODEL);
    const float inv = rsqrtf(var + 1e-12f);

#pragma unroll
    for (int i = 0; i < 3; ++i) {
        int c = t + i * 256;
        out[(size_t)row * DMODEL + c] = (vals[i] - mu) * inv * gw[c] + bw[c];
    }
}

// ---------------------------------------------------------------------------
extern "C" void kernel_launch(void* const* d_in, const int* in_sizes, int n_in,
                              void* d_out, int out_size, void* d_ws, size_t ws_size,
                              hipStream_t stream)
{
    const float* x    = (const float*)d_in[0];
    const int*   mask = (const int*)d_in[1];
    const float* Wq = (const float*)d_in[2];
    const float* bq = (const float*)d_in[3];
    const float* Wk = (const float*)d_in[4];
    const float* bk = (const float*)d_in[5];
    const float* Wv = (const float*)d_in[6];
    const float* bv = (const float*)d_in[7];
    const float* Wo = (const float*)d_in[8];
    const float* bo = (const float*)d_in[9];
    const float* ln1g = (const float*)d_in[10];
    const float* ln1b = (const float*)d_in[11];
    const float* W1 = (const float*)d_in[12];
    const float* b1 = (const float*)d_in[13];
    const float* W2 = (const float*)d_in[14];
    const float* b2 = (const float*)d_in[15];
    const float* ln2g = (const float*)d_in[16];
    const float* ln2b = (const float*)d_in[17];

    float* ws = (float*)d_ws;
    float* buf0  = ws;             // h (layer input / output)
    float* buf1  = ws + ND;        // q, then sa
    float* buf2  = ws + 2 * ND;    // k, then h2
    float* buf3  = ws + 3 * ND;    // v, then ffn_out
    float* buf4  = ws + 4 * ND;    // ctx
    float* bufFF = ws + 5 * ND;    // N x FF intermediate

    hipMemcpyAsync(buf0, x, ND * sizeof(float), hipMemcpyDeviceToDevice, stream);

    const dim3 gD(DMODEL / BN, NTOK / BM);   // (6, 32)
    const dim3 gFF(FFDIM / BN, NTOK / BM);   // (24, 32)
    const dim3 gA(SEQ / QT, NHEAD, BATCH);   // (8, 12, 8)

    for (int l = 0; l < NLAYER; ++l) {
        const float* Wq_l = Wq + (size_t)l * DMODEL * DMODEL;
        const float* Wk_l = Wk + (size_t)l * DMODEL * DMODEL;
        const float* Wv_l = Wv + (size_t)l * DMODEL * DMODEL;
        const float* Wo_l = Wo + (size_t)l * DMODEL * DMODEL;
        const float* W1_l = W1 + (size_t)l * DMODEL * FFDIM;
        const float* W2_l = W2 + (size_t)l * FFDIM * DMODEL;
        const float* bq_l = bq + (size_t)l * DMODEL;
        const float* bk_l = bk + (size_t)l * DMODEL;
        const float* bv_l = bv + (size_t)l * DMODEL;
        const float* bo_l = bo + (size_t)l * DMODEL;
        const float* b1_l = b1 + (size_t)l * FFDIM;
        const float* b2_l = b2 + (size_t)l * DMODEL;

        gemm_bias<<<gD, 256, 0, stream>>>(buf0, Wq_l, bq_l, buf1, NTOK, DMODEL, DMODEL, 2);
        gemm_bias<<<gD, 256, 0, stream>>>(buf0, Wk_l, bk_l, buf2, NTOK, DMODEL, DMODEL, 0);
        gemm_bias<<<gD, 256, 0, stream>>>(buf0, Wv_l, bv_l, buf3, NTOK, DMODEL, DMODEL, 0);

        attn_flash<<<gA, 256, 0, stream>>>(buf1, buf2, buf3, mask, buf4);

        gemm_bias<<<gD, 256, 0, stream>>>(buf4, Wo_l, bo_l, buf1, NTOK, DMODEL, DMODEL, 0);

        add_ln_kernel<<<NTOK, 256, 0, stream>>>(buf1, buf0, ln1g + (size_t)l * DMODEL,
                                                ln1b + (size_t)l * DMODEL, buf2);

        gemm_bias<<<gFF, 256, 0, stream>>>(buf2, W1_l, b1_l, bufFF, NTOK, DMODEL, FFDIM, 1);
        gemm_bias<<<gD, 256, 0, stream>>>(bufFF, W2_l, b2_l, buf3, NTOK, FFDIM, DMODEL, 0);

        float* hout = (l == NLAYER - 1) ? (float*)d_out : buf0;
        add_ln_kernel<<<NTOK, 256, 0, stream>>>(buf3, buf2, ln2g + (size_t)l * DMODEL,
                                                ln2b + (size_t)l * DMODEL, hout);
    }
}

// Round 3
// 2798.487 us; speedup vs baseline: 5.4327x; 3.1960x over previous
//
#include <hip/hip_runtime.h>
#include <math.h>

#define NLAYER 6
#define DMODEL 768
#define NHEAD 12
#define DHEAD 64
#define FFDIM 3072
#define SEQ 512
#define BATCH 8
#define NTOK (BATCH * SEQ) /* 4096 */
#define ND ((size_t)NTOK * DMODEL)

typedef __bf16 bf16_t;
typedef __bf16 bf16x8 __attribute__((ext_vector_type(8)));
typedef float f32x4 __attribute__((ext_vector_type(4)));

__device__ __forceinline__ float bf2f(ushort u) {
    return __uint_as_float(((unsigned int)u) << 16);
}
union BFU { __bf16 h; ushort u; };
__device__ __forceinline__ ushort f2b(float x) { BFU c; c.h = (__bf16)x; return c.u; }

#define GLDS(gp, lp) __builtin_amdgcn_global_load_lds( \
    (const __attribute__((address_space(1))) void*)(gp), \
    (__attribute__((address_space(3))) void*)(lp), 16, 0, 0)

// ---------------------------------------------------------------------------
// bf16 MFMA GEMM (m97 structure): C = act(A @ B + bias)
// A: M x K bf16 row-major.  Bt: N x K bf16 row-major (= B transposed).
// 128x128 tile, BK=32, 256 threads (4 waves), wave = 64x64 via 4x4 MFMAs.
// LDS chunk swizzle: chunk kc of row r holds global k-chunk kc ^ ((r>>1)&3),
// applied identically at stage (gptr select) and fragment read.
// act: 0 none, 1 exact gelu, 2 *0.125.  Writes Cf (fp32) or Cb (bf16).
// ---------------------------------------------------------------------------
__global__ __launch_bounds__(256) void gemm_mfma(
    const ushort* __restrict__ A, const ushort* __restrict__ Bt,
    const float* __restrict__ bias, float* __restrict__ Cf,
    ushort* __restrict__ Cb, int M, int K, int N, int act)
{
    __shared__ __align__(16) ushort As[4096];   // 128 rows x 32 k
    __shared__ __align__(16) ushort Bs[4096];   // 128 cols x 32 k

    const int t = threadIdx.x;
    const int w = t >> 6, l = t & 63;
    const int wr = w >> 1, wc = w & 1;
    const int row0 = blockIdx.y * 128, col0 = blockIdx.x * 128;

    f32x4 acc[4][4];
#pragma unroll
    for (int mi = 0; mi < 4; ++mi)
#pragma unroll
        for (int ni = 0; ni < 4; ++ni)
#pragma unroll
            for (int e = 0; e < 4; ++e) acc[mi][ni][e] = 0.f;

    // staging: instr i covers chunk c = i*256 + t; chunk c = (row r=c>>2, kc=c&3)
    const int c0 = t,       r0 = c0 >> 2, kg0 = (c0 & 3) ^ ((r0 >> 1) & 3);
    const int c1 = t + 256, r1 = c1 >> 2, kg1 = (c1 & 3) ^ ((r1 >> 1) & 3);
    const ushort* gA0 = A + (size_t)(row0 + r0) * K + kg0 * 8;
    const ushort* gA1 = A + (size_t)(row0 + r1) * K + kg1 * 8;
    const ushort* gB0 = Bt + (size_t)(col0 + r0) * K + kg0 * 8;
    const ushort* gB1 = Bt + (size_t)(col0 + r1) * K + kg1 * 8;
    ushort* lA0 = &As[w * 512];          // wave-uniform LDS bases
    ushort* lA1 = &As[2048 + w * 512];
    ushort* lB0 = &Bs[w * 512];
    ushort* lB1 = &Bs[2048 + w * 512];

    // fragment read offsets (ushorts)
    const int lm = l & 15, lq = l >> 4;
    int aoff[4], boff[4];
#pragma unroll
    for (int mi = 0; mi < 4; ++mi) {
        int m = wr * 64 + mi * 16 + lm;
        aoff[mi] = m * 32 + (lq ^ ((m >> 1) & 3)) * 8;
    }
#pragma unroll
    for (int ni = 0; ni < 4; ++ni) {
        int n = wc * 64 + ni * 16 + lm;
        boff[ni] = n * 32 + (lq ^ ((n >> 1) & 3)) * 8;
    }

    for (int k0 = 0; k0 < K; k0 += 32) {
        GLDS(gA0 + k0, lA0);
        GLDS(gA1 + k0, lA1);
        GLDS(gB0 + k0, lB0);
        GLDS(gB1 + k0, lB1);
        __syncthreads();

        bf16x8 af[4], bfr[4];
#pragma unroll
        for (int mi = 0; mi < 4; ++mi) af[mi] = *(const bf16x8*)&As[aoff[mi]];
#pragma unroll
        for (int ni = 0; ni < 4; ++ni) bfr[ni] = *(const bf16x8*)&Bs[boff[ni]];

#pragma unroll
        for (int mi = 0; mi < 4; ++mi)
#pragma unroll
            for (int ni = 0; ni < 4; ++ni)
                acc[mi][ni] = __builtin_amdgcn_mfma_f32_16x16x32_bf16(
                    af[mi], bfr[ni], acc[mi][ni], 0, 0, 0);
        __syncthreads();
    }

    // epilogue: C/D layout col = lane&15, row = (lane>>4)*4 + reg
#pragma unroll
    for (int mi = 0; mi < 4; ++mi) {
        int rowb = row0 + wr * 64 + mi * 16 + lq * 4;
#pragma unroll
        for (int ni = 0; ni < 4; ++ni) {
            int col = col0 + wc * 64 + ni * 16 + lm;
            float bv = bias[col];
#pragma unroll
            for (int r = 0; r < 4; ++r) {
                float v = acc[mi][ni][r] + bv;
                if (act == 1)      v = 0.5f * v * (1.0f + erff(v * 0.70710678118654752f));
                else if (act == 2) v *= 0.125f;
                size_t idx = (size_t)(rowb + r) * N + col;
                if (Cb) ((bf16_t*)Cb)[idx] = (bf16_t)v;
                else    Cf[idx] = v;
            }
        }
    }
}

// ---------------------------------------------------------------------------
// Per-layer weight transpose+convert: K x N fp32 -> N x K bf16.
// One launch handles Wq,Wk,Wv,Wo (4 x 768x768), W1 (768x3072), W2 (3072x768).
// ---------------------------------------------------------------------------
__global__ __launch_bounds__(256) void transpose_w(
    const float* __restrict__ Wq, const float* __restrict__ Wk,
    const float* __restrict__ Wv, const float* __restrict__ Wo,
    const float* __restrict__ W1, const float* __restrict__ W2,
    ushort* __restrict__ Wqt, ushort* __restrict__ Wkt,
    ushort* __restrict__ Wvt, ushort* __restrict__ Wot,
    ushort* __restrict__ W1t, ushort* __restrict__ W2t)
{
    __shared__ float tile[32][33];
    const int bid = blockIdx.x;
    const float* src; ushort* dst; int K, N, tx, ty;
    if (bid < 2304) {
        int m = bid / 576, tl = bid % 576;
        src = (m == 0) ? Wq : (m == 1) ? Wk : (m == 2) ? Wv : Wo;
        dst = (m == 0) ? Wqt : (m == 1) ? Wkt : (m == 2) ? Wvt : Wot;
        K = 768; N = 768; tx = tl % 24; ty = tl / 24;
    } else if (bid < 4608) {
        int tl = bid - 2304;
        src = W1; dst = W1t; K = 768; N = 3072; tx = tl % 96; ty = tl / 96;
    } else {
        int tl = bid - 4608;
        src = W2; dst = W2t; K = 3072; N = 768; tx = tl % 24; ty = tl / 24;
    }
    const int t = threadIdx.x;
    const int lx = t & 31, ly = t >> 5;
    const int n0 = tx * 32, k0 = ty * 32;
#pragma unroll
    for (int i = 0; i < 4; ++i)
        tile[lx][ly + i * 8] = src[(size_t)(k0 + ly + i * 8) * N + n0 + lx];
    __syncthreads();
#pragma unroll
    for (int i = 0; i < 4; ++i)
        ((bf16_t*)dst)[(size_t)(n0 + ly + i * 8) * K + k0 + lx] =
            (bf16_t)tile[ly + i * 8][lx];
}

// ---------------------------------------------------------------------------
// fp32 -> bf16 convert (x -> hb), 4 elems/thread
// ---------------------------------------------------------------------------
__global__ __launch_bounds__(256) void f2bf_kernel(
    const float* __restrict__ src, ushort* __restrict__ dst)
{
    const size_t i = ((size_t)blockIdx.x * 256 + threadIdx.x) * 4;
    float4 v = *(const float4*)(src + i);
    ushort4 o;
    o.x = f2b(v.x); o.y = f2b(v.y); o.z = f2b(v.z); o.w = f2b(v.w);
    *(ushort4*)(dst + i) = o;
}

// ---------------------------------------------------------------------------
// Flash attention (fp32 math): q fp32, k/v bf16 in, ctx bf16 out.
// Same structure as round 2; only staging/output dtype changed.
// ---------------------------------------------------------------------------
#define QT 64
#define KT 64

__global__ __launch_bounds__(256) void attn_flash(
    const float* __restrict__ q, const ushort* __restrict__ kbp,
    const ushort* __restrict__ vbp, const int* __restrict__ mask,
    ushort* __restrict__ ctxb)
{
    __shared__ float Ks[KT][68];
    __shared__ float Vs[KT][68];
    __shared__ float Ps[QT][66];
    __shared__ float Ma[KT];

    const int qt = blockIdx.x;
    const int h  = blockIdx.y;
    const int b  = blockIdx.z;
    const int t  = threadIdx.x;
    const int c  = t & 7;
    const int rp = t >> 3;
    const int row0 = rp;
    const int row1 = rp + 32;

    const size_t qbase0 = ((size_t)(b * SEQ + qt * QT + row0)) * DMODEL + h * DHEAD;
    const size_t qbase1 = ((size_t)(b * SEQ + qt * QT + row1)) * DMODEL + h * DHEAD;
    const float4* q0 = (const float4*)(q + qbase0);
    const float4* q1 = (const float4*)(q + qbase1);

    float m0 = -3.4e38f, m1 = -3.4e38f;
    float l0 = 0.f, l1 = 0.f;
    float O0[8], O1[8];
#pragma unroll
    for (int u = 0; u < 8; ++u) { O0[u] = 0.f; O1[u] = 0.f; }

    for (int kt = 0; kt < SEQ / KT; ++kt) {
        // stage K/V (bf16 -> fp32 LDS)
#pragma unroll
        for (int i = 0; i < 2; ++i) {
            int ch = t + i * 256;      // 0..511
            int r  = ch >> 3;          // key row 0..63
            int d8 = ch & 7;           // 8-dim chunk
            size_t g = ((size_t)(b * SEQ + kt * KT + r)) * DMODEL + h * DHEAD + d8 * 8;
            uint4 kv4 = *(const uint4*)(kbp + g);
            uint4 vv4 = *(const uint4*)(vbp + g);
            const ushort* ku = (const ushort*)&kv4;
            const ushort* vu = (const ushort*)&vv4;
            int sw = (r >> 3) & 7;
            int ka = ((d8 * 2) ^ sw) * 4;
            int kb2 = ((d8 * 2 + 1) ^ sw) * 4;
#pragma unroll
            for (int u = 0; u < 4; ++u) Ks[r][ka + u]  = bf2f(ku[u]);
#pragma unroll
            for (int u = 0; u < 4; ++u) Ks[r][kb2 + u] = bf2f(ku[4 + u]);
#pragma unroll
            for (int u = 0; u < 8; ++u) Vs[r][d8 * 8 + u] = bf2f(vu[u]);
        }
        if (t < KT) Ma[t] = (mask[b * SEQ + kt * KT + t] == 0) ? -1e9f : 0.f;
        __syncthreads();

        float s0[8], s1[8];
#pragma unroll
        for (int jj = 0; jj < 8; ++jj) { s0[jj] = 0.f; s1[jj] = 0.f; }

#pragma unroll
        for (int d4 = 0; d4 < 16; ++d4) {
            float4 qa = q0[d4];
            float4 qb = q1[d4];
#pragma unroll
            for (int jj = 0; jj < 8; ++jj) {
                float4 kv = *(const float4*)&Ks[c * 8 + jj][(d4 ^ c) * 4];
                s0[jj] += qa.x * kv.x + qa.y * kv.y + qa.z * kv.z + qa.w * kv.w;
                s1[jj] += qb.x * kv.x + qb.y * kv.y + qb.z * kv.z + qb.w * kv.w;
            }
        }

        float tm0 = -3.4e38f, tm1 = -3.4e38f;
#pragma unroll
        for (int jj = 0; jj < 8; ++jj) {
            s0[jj] += Ma[c * 8 + jj];
            s1[jj] += Ma[c * 8 + jj];
            tm0 = fmaxf(tm0, s0[jj]);
            tm1 = fmaxf(tm1, s1[jj]);
        }
#pragma unroll
        for (int off = 1; off < 8; off <<= 1) {
            tm0 = fmaxf(tm0, __shfl_xor(tm0, off));
            tm1 = fmaxf(tm1, __shfl_xor(tm1, off));
        }
        const float mn0 = fmaxf(m0, tm0);
        const float mn1 = fmaxf(m1, tm1);
        const float sc0 = __expf(m0 - mn0);
        const float sc1 = __expf(m1 - mn1);
        float ts0 = 0.f, ts1 = 0.f;
#pragma unroll
        for (int jj = 0; jj < 8; ++jj) {
            float p0 = __expf(s0[jj] - mn0);
            float p1 = __expf(s1[jj] - mn1);
            Ps[row0][c * 8 + jj] = p0;
            Ps[row1][c * 8 + jj] = p1;
            ts0 += p0;
            ts1 += p1;
        }
#pragma unroll
        for (int off = 1; off < 8; off <<= 1) {
            ts0 += __shfl_xor(ts0, off);
            ts1 += __shfl_xor(ts1, off);
        }
        l0 = l0 * sc0 + ts0;
        l1 = l1 * sc1 + ts1;
        m0 = mn0;
        m1 = mn1;
#pragma unroll
        for (int u = 0; u < 8; ++u) { O0[u] *= sc0; O1[u] *= sc1; }
        __syncthreads();

#pragma unroll 4
        for (int j = 0; j < KT; ++j) {
            float p0 = Ps[row0][j];
            float p1 = Ps[row1][j];
            float4 va = *(const float4*)&Vs[j][c * 8];
            float4 vb = *(const float4*)&Vs[j][c * 8 + 4];
            O0[0] += p0 * va.x; O0[1] += p0 * va.y; O0[2] += p0 * va.z; O0[3] += p0 * va.w;
            O0[4] += p0 * vb.x; O0[5] += p0 * vb.y; O0[6] += p0 * vb.z; O0[7] += p0 * vb.w;
            O1[0] += p1 * va.x; O1[1] += p1 * va.y; O1[2] += p1 * va.z; O1[3] += p1 * va.w;
            O1[4] += p1 * vb.x; O1[5] += p1 * vb.y; O1[6] += p1 * vb.z; O1[7] += p1 * vb.w;
        }
        __syncthreads();
    }

    const float i0 = 1.f / l0;
    const float i1 = 1.f / l1;
    uint4 oa, ob;
    ushort* pa = (ushort*)&oa;
    ushort* pb = (ushort*)&ob;
#pragma unroll
    for (int u = 0; u < 8; ++u) { pa[u] = f2b(O0[u] * i0); pb[u] = f2b(O1[u] * i1); }
    *(uint4*)&ctxb[qbase0 + c * 8] = oa;
    *(uint4*)&ctxb[qbase1 + c * 8] = ob;
}

// ---------------------------------------------------------------------------
// out = LayerNorm(a + b); writes fp32 (residual) and bf16 (next GEMM input)
// ---------------------------------------------------------------------------
__global__ __launch_bounds__(256) void add_ln_kernel(
    const float* __restrict__ a, const float* __restrict__ b,
    const float* __restrict__ gw, const float* __restrict__ bw,
    float* __restrict__ out, ushort* __restrict__ outb)
{
    const int row = blockIdx.x;
    const int t = threadIdx.x;
    __shared__ float red[8];

    const float* ar = a + (size_t)row * DMODEL;
    const float* br = b + (size_t)row * DMODEL;

    float vals[3];
    float s = 0.f;
#pragma unroll
    for (int i = 0; i < 3; ++i) {
        vals[i] = ar[t + i * 256] + br[t + i * 256];
        s += vals[i];
    }
#pragma unroll
    for (int off = 32; off > 0; off >>= 1) s += __shfl_down(s, off, 64);
    if ((t & 63) == 0) red[t >> 6] = s;
    __syncthreads();
    const float mu = (red[0] + red[1] + red[2] + red[3]) * (1.0f / DMODEL);

    float vs = 0.f;
#pragma unroll
    for (int i = 0; i < 3; ++i) {
        float d = vals[i] - mu;
        vs += d * d;
    }
#pragma unroll
    for (int off = 32; off > 0; off >>= 1) vs += __shfl_down(vs, off, 64);
    if ((t & 63) == 0) red[4 + (t >> 6)] = vs;
    __syncthreads();
    const float var = (red[4] + red[5] + red[6] + red[7]) * (1.0f / DMODEL);
    const float inv = rsqrtf(var + 1e-12f);

#pragma unroll
    for (int i = 0; i < 3; ++i) {
        int c = t + i * 256;
        float v = (vals[i] - mu) * inv * gw[c] + bw[c];
        out[(size_t)row * DMODEL + c] = v;
        ((bf16_t*)outb)[(size_t)row * DMODEL + c] = (bf16_t)v;
    }
}

// ---------------------------------------------------------------------------
extern "C" void kernel_launch(void* const* d_in, const int* in_sizes, int n_in,
                              void* d_out, int out_size, void* d_ws, size_t ws_size,
                              hipStream_t stream)
{
    const float* x    = (const float*)d_in[0];
    const int*   mask = (const int*)d_in[1];
    const float* Wq = (const float*)d_in[2];
    const float* bq = (const float*)d_in[3];
    const float* Wk = (const float*)d_in[4];
    const float* bk = (const float*)d_in[5];
    const float* Wv = (const float*)d_in[6];
    const float* bv = (const float*)d_in[7];
    const float* Wo = (const float*)d_in[8];
    const float* bo = (const float*)d_in[9];
    const float* ln1g = (const float*)d_in[10];
    const float* ln1b = (const float*)d_in[11];
    const float* W1 = (const float*)d_in[12];
    const float* b1 = (const float*)d_in[13];
    const float* W2 = (const float*)d_in[14];
    const float* b2 = (const float*)d_in[15];
    const float* ln2g = (const float*)d_in[16];
    const float* ln2b = (const float*)d_in[17];

    // ---- workspace layout (~108.5 MB) ----
    float* f32b = (float*)d_ws;
    float* hbuf = f32b;            // h residual (fp32)
    float* qf   = f32b + ND;       // q (fp32)
    float* f1   = f32b + 2 * ND;   // sa / ffn_out (fp32)
    float* h2   = f32b + 3 * ND;   // h2 residual (fp32)
    ushort* ub  = (ushort*)(f32b + 4 * ND);
    ushort* kbu = ub;                          // k bf16
    ushort* vbu = ub + ND;                     // v bf16
    ushort* hb  = ub + 2 * ND;                 // h bf16 (aliases h2b)
    ushort* U   = ub + 3 * ND;                 // gelu-out bf16 (NTOK x FF)
    ushort* ctxb = U;                          // ctx bf16 (aliases U; disjoint lifetime)
    ushort* Wqt = U + (size_t)NTOK * FFDIM;
    ushort* Wkt = Wqt + 768 * 768;
    ushort* Wvt = Wkt + 768 * 768;
    ushort* Wot = Wvt + 768 * 768;
    ushort* W1t = Wot + 768 * 768;             // 3072 x 768
    ushort* W2t = W1t + (size_t)768 * 3072;    // 768 x 3072

    hipMemcpyAsync(hbuf, x, ND * sizeof(float), hipMemcpyDeviceToDevice, stream);
    f2bf_kernel<<<(int)(ND / 1024), 256, 0, stream>>>(x, hb);

    const dim3 gD(6, 32);      // N=768
    const dim3 gFF(24, 32);    // N=3072
    const dim3 gA(SEQ / QT, NHEAD, BATCH);

    for (int l = 0; l < NLAYER; ++l) {
        const float* Wq_l = Wq + (size_t)l * DMODEL * DMODEL;
        const float* Wk_l = Wk + (size_t)l * DMODEL * DMODEL;
        const float* Wv_l = Wv + (size_t)l * DMODEL * DMODEL;
        const float* Wo_l = Wo + (size_t)l * DMODEL * DMODEL;
        const float* W1_l = W1 + (size_t)l * DMODEL * FFDIM;
        const float* W2_l = W2 + (size_t)l * FFDIM * DMODEL;

        transpose_w<<<6912, 256, 0, stream>>>(Wq_l, Wk_l, Wv_l, Wo_l, W1_l, W2_l,
                                              Wqt, Wkt, Wvt, Wot, W1t, W2t);

        // projections: q -> fp32 (scaled), k/v -> bf16
        gemm_mfma<<<gD, 256, 0, stream>>>(hb, Wqt, bq + (size_t)l * DMODEL,
                                          qf, nullptr, NTOK, DMODEL, DMODEL, 2);
        gemm_mfma<<<gD, 256, 0, stream>>>(hb, Wkt, bk + (size_t)l * DMODEL,
                                          nullptr, kbu, NTOK, DMODEL, DMODEL, 0);
        gemm_mfma<<<gD, 256, 0, stream>>>(hb, Wvt, bv + (size_t)l * DMODEL,
                                          nullptr, vbu, NTOK, DMODEL, DMODEL, 0);

        attn_flash<<<gA, 256, 0, stream>>>(qf, kbu, vbu, mask, ctxb);

        // sa = ctx @ Wo + bo (fp32)
        gemm_mfma<<<gD, 256, 0, stream>>>(ctxb, Wot, bo + (size_t)l * DMODEL,
                                          f1, nullptr, NTOK, DMODEL, DMODEL, 0);

        // h2 = LN(sa + h): fp32 + bf16 (h2b aliases hb — safe, hb consumed)
        add_ln_kernel<<<NTOK, 256, 0, stream>>>(f1, hbuf, ln1g + (size_t)l * DMODEL,
                                                ln1b + (size_t)l * DMODEL, h2, hb);

        // ffn
        gemm_mfma<<<gFF, 256, 0, stream>>>(hb, W1t, b1 + (size_t)l * FFDIM,
                                           nullptr, U, NTOK, DMODEL, FFDIM, 1);
        gemm_mfma<<<gD, 256, 0, stream>>>(U, W2t, b2 + (size_t)l * DMODEL,
                                          f1, nullptr, NTOK, FFDIM, DMODEL, 0);

        // h = LN(ffn_out + h2); last layer -> d_out
        float* hout = (l == NLAYER - 1) ? (float*)d_out : hbuf;
        add_ln_kernel<<<NTOK, 256, 0, stream>>>(f1, h2, ln2g + (size_t)l * DMODEL,
                                                ln2b + (size_t)l * DMODEL, hout, hb);
    }
}

// Round 4
// 1486.706 us; speedup vs baseline: 10.2262x; 1.8823x over previous
//
#include <hip/hip_runtime.h>
#include <math.h>

#define NLAYER 6
#define DMODEL 768
#define NHEAD 12
#define DHEAD 64
#define FFDIM 3072
#define SEQ 512
#define BATCH 8
#define NTOK (BATCH * SEQ) /* 4096 */
#define ND ((size_t)NTOK * DMODEL)

typedef __bf16 bf16_t;
typedef __bf16 bf16x8 __attribute__((ext_vector_type(8)));
typedef float f32x4 __attribute__((ext_vector_type(4)));

__device__ __forceinline__ float bf2f(ushort u) {
    return __uint_as_float(((unsigned int)u) << 16);
}
union BFU { __bf16 h; ushort u; };
__device__ __forceinline__ ushort f2b(float x) { BFU c; c.h = (__bf16)x; return c.u; }

#define GLDS(gp, lp) __builtin_amdgcn_global_load_lds( \
    (const __attribute__((address_space(1))) void*)(gp), \
    (__attribute__((address_space(3))) void*)(lp), 16, 0, 0)

// ---------------------------------------------------------------------------
// bf16 MFMA GEMM (m97 structure): C = act(A @ B + bias)
// A: M x K bf16 row-major.  Bt: N x K bf16 row-major.
// 128x128 tile, BK=32, 256 threads (4 waves), wave = 64x64 via 4x4 MFMAs.
// act: 0 none, 1 exact gelu.  Writes Cf (fp32) or Cb (bf16).
// ---------------------------------------------------------------------------
__global__ __launch_bounds__(256) void gemm_mfma(
    const ushort* __restrict__ A, const ushort* __restrict__ Bt,
    const float* __restrict__ bias, float* __restrict__ Cf,
    ushort* __restrict__ Cb, int M, int K, int N, int act)
{
    __shared__ __align__(16) ushort As[4096];
    __shared__ __align__(16) ushort Bs[4096];

    const int t = threadIdx.x;
    const int w = t >> 6, l = t & 63;
    const int wr = w >> 1, wc = w & 1;
    const int row0 = blockIdx.y * 128, col0 = blockIdx.x * 128;

    f32x4 acc[4][4];
#pragma unroll
    for (int mi = 0; mi < 4; ++mi)
#pragma unroll
        for (int ni = 0; ni < 4; ++ni)
#pragma unroll
            for (int e = 0; e < 4; ++e) acc[mi][ni][e] = 0.f;

    const int c0 = t,       r0 = c0 >> 2, kg0 = (c0 & 3) ^ ((r0 >> 1) & 3);
    const int c1 = t + 256, r1 = c1 >> 2, kg1 = (c1 & 3) ^ ((r1 >> 1) & 3);
    const ushort* gA0 = A + (size_t)(row0 + r0) * K + kg0 * 8;
    const ushort* gA1 = A + (size_t)(row0 + r1) * K + kg1 * 8;
    const ushort* gB0 = Bt + (size_t)(col0 + r0) * K + kg0 * 8;
    const ushort* gB1 = Bt + (size_t)(col0 + r1) * K + kg1 * 8;
    ushort* lA0 = &As[w * 512];
    ushort* lA1 = &As[2048 + w * 512];
    ushort* lB0 = &Bs[w * 512];
    ushort* lB1 = &Bs[2048 + w * 512];

    const int lm = l & 15, lq = l >> 4;
    int aoff[4], boff[4];
#pragma unroll
    for (int mi = 0; mi < 4; ++mi) {
        int m = wr * 64 + mi * 16 + lm;
        aoff[mi] = m * 32 + (lq ^ ((m >> 1) & 3)) * 8;
    }
#pragma unroll
    for (int ni = 0; ni < 4; ++ni) {
        int n = wc * 64 + ni * 16 + lm;
        boff[ni] = n * 32 + (lq ^ ((n >> 1) & 3)) * 8;
    }

    for (int k0 = 0; k0 < K; k0 += 32) {
        GLDS(gA0 + k0, lA0);
        GLDS(gA1 + k0, lA1);
        GLDS(gB0 + k0, lB0);
        GLDS(gB1 + k0, lB1);
        __syncthreads();

        bf16x8 af[4], bfr[4];
#pragma unroll
        for (int mi = 0; mi < 4; ++mi) af[mi] = *(const bf16x8*)&As[aoff[mi]];
#pragma unroll
        for (int ni = 0; ni < 4; ++ni) bfr[ni] = *(const bf16x8*)&Bs[boff[ni]];

#pragma unroll
        for (int mi = 0; mi < 4; ++mi)
#pragma unroll
            for (int ni = 0; ni < 4; ++ni)
                acc[mi][ni] = __builtin_amdgcn_mfma_f32_16x16x32_bf16(
                    af[mi], bfr[ni], acc[mi][ni], 0, 0, 0);
        __syncthreads();
    }

#pragma unroll
    for (int mi = 0; mi < 4; ++mi) {
        int rowb = row0 + wr * 64 + mi * 16 + lq * 4;
#pragma unroll
        for (int ni = 0; ni < 4; ++ni) {
            int col = col0 + wc * 64 + ni * 16 + lm;
            float bv = bias[col];
#pragma unroll
            for (int r = 0; r < 4; ++r) {
                float v = acc[mi][ni][r] + bv;
                if (act == 1) v = 0.5f * v * (1.0f + erff(v * 0.70710678118654752f));
                size_t idx = (size_t)(rowb + r) * N + col;
                if (Cb) ((bf16_t*)Cb)[idx] = (bf16_t)v;
                else    Cf[idx] = v;
            }
        }
    }
}

// ---------------------------------------------------------------------------
// Fused QKV GEMM: A (M x 768) @ Wqkvt^T (2304 x 768) -> q (scaled, token-major
// bf16), k (token-major bf16), v (TRANSPOSED [b,h,d,s] bf16 for attn PV).
// Segment is block-uniform (col0 multiples of 128; boundaries at 768, 1536).
// ---------------------------------------------------------------------------
__global__ __launch_bounds__(256) void gemm_qkv(
    const ushort* __restrict__ A, const ushort* __restrict__ Bt,
    const float* __restrict__ bq, const float* __restrict__ bk,
    const float* __restrict__ bv,
    ushort* __restrict__ qb, ushort* __restrict__ kb, ushort* __restrict__ vtb)
{
    __shared__ __align__(16) ushort As[4096];
    __shared__ __align__(16) ushort Bs[4096];

    const int K = DMODEL;
    const int t = threadIdx.x;
    const int w = t >> 6, l = t & 63;
    const int wr = w >> 1, wc = w & 1;
    const int row0 = blockIdx.y * 128, col0 = blockIdx.x * 128;
    const int seg = blockIdx.x / 6;            // 0=q 1=k 2=v

    f32x4 acc[4][4];
#pragma unroll
    for (int mi = 0; mi < 4; ++mi)
#pragma unroll
        for (int ni = 0; ni < 4; ++ni)
#pragma unroll
            for (int e = 0; e < 4; ++e) acc[mi][ni][e] = 0.f;

    const int c0 = t,       r0 = c0 >> 2, kg0 = (c0 & 3) ^ ((r0 >> 1) & 3);
    const int c1 = t + 256, r1 = c1 >> 2, kg1 = (c1 & 3) ^ ((r1 >> 1) & 3);
    const ushort* gA0 = A + (size_t)(row0 + r0) * K + kg0 * 8;
    const ushort* gA1 = A + (size_t)(row0 + r1) * K + kg1 * 8;
    const ushort* gB0 = Bt + (size_t)(col0 + r0) * K + kg0 * 8;
    const ushort* gB1 = Bt + (size_t)(col0 + r1) * K + kg1 * 8;
    ushort* lA0 = &As[w * 512];
    ushort* lA1 = &As[2048 + w * 512];
    ushort* lB0 = &Bs[w * 512];
    ushort* lB1 = &Bs[2048 + w * 512];

    const int lm = l & 15, lq = l >> 4;
    int aoff[4], boff[4];
#pragma unroll
    for (int mi = 0; mi < 4; ++mi) {
        int m = wr * 64 + mi * 16 + lm;
        aoff[mi] = m * 32 + (lq ^ ((m >> 1) & 3)) * 8;
    }
#pragma unroll
    for (int ni = 0; ni < 4; ++ni) {
        int n = wc * 64 + ni * 16 + lm;
        boff[ni] = n * 32 + (lq ^ ((n >> 1) & 3)) * 8;
    }

    for (int k0 = 0; k0 < K; k0 += 32) {
        GLDS(gA0 + k0, lA0);
        GLDS(gA1 + k0, lA1);
        GLDS(gB0 + k0, lB0);
        GLDS(gB1 + k0, lB1);
        __syncthreads();

        bf16x8 af[4], bfr[4];
#pragma unroll
        for (int mi = 0; mi < 4; ++mi) af[mi] = *(const bf16x8*)&As[aoff[mi]];
#pragma unroll
        for (int ni = 0; ni < 4; ++ni) bfr[ni] = *(const bf16x8*)&Bs[boff[ni]];

#pragma unroll
        for (int mi = 0; mi < 4; ++mi)
#pragma unroll
            for (int ni = 0; ni < 4; ++ni)
                acc[mi][ni] = __builtin_amdgcn_mfma_f32_16x16x32_bf16(
                    af[mi], bfr[ni], acc[mi][ni], 0, 0, 0);
        __syncthreads();
    }

    const float* bp = (seg == 0) ? bq : (seg == 1) ? bk : bv;
    const float sc = (seg == 0) ? 0.125f : 1.0f;
#pragma unroll
    for (int mi = 0; mi < 4; ++mi) {
        int rowb = row0 + wr * 64 + mi * 16 + lq * 4;   // 4-aligned, tile 128-aligned
#pragma unroll
        for (int ni = 0; ni < 4; ++ni) {
            int col = col0 + wc * 64 + ni * 16 + lm;
            int lcol = col - seg * 768;
            float bvv = bp[lcol];
            if (seg == 2) {
                int hh = lcol >> 6, dd = lcol & 63;
                int bb = rowb >> 9, ss = rowb & 511;    // 4 tokens same batch
                ushort4 o;
                o.x = f2b(acc[mi][ni][0] + bvv);
                o.y = f2b(acc[mi][ni][1] + bvv);
                o.z = f2b(acc[mi][ni][2] + bvv);
                o.w = f2b(acc[mi][ni][3] + bvv);
                *(ushort4*)&vtb[(((size_t)(bb * NHEAD + hh)) * DHEAD + dd) * SEQ + ss] = o;
            } else {
                ushort* dst = seg ? kb : qb;
#pragma unroll
                for (int r = 0; r < 4; ++r)
                    dst[(size_t)(rowb + r) * DMODEL + lcol] = f2b((acc[mi][ni][r] + bvv) * sc);
            }
        }
    }
}

// ---------------------------------------------------------------------------
// MFMA flash attention. Block = (64-q tile, head, batch), 256 thr / 4 waves.
// Wave w owns q-rows [w*16, w*16+16). Per 64-key tile: QK^T (2 MFMA k-steps
// x 4 key-ntiles), online softmax on C-layout regs, P->LDS (wave-private
// rows, no barrier), PV with B = V^T staged from vtb [b,h,d,s].
// All tiles stride-72 ushorts => <=2-way LDS bank aliasing (free).
// ---------------------------------------------------------------------------
#define QSTR 72

__global__ __launch_bounds__(256) void attn_mfma(
    const ushort* __restrict__ qb, const ushort* __restrict__ kb,
    const ushort* __restrict__ vtb, const int* __restrict__ mask,
    ushort* __restrict__ ctxb)
{
    __shared__ __align__(16) ushort Qs[64 * QSTR];
    __shared__ __align__(16) ushort Ks[64 * QSTR];
    __shared__ __align__(16) ushort Vs[64 * QSTR];
    __shared__ __align__(16) ushort Ps[64 * QSTR];
    __shared__ float Ma[64];

    const int qt = blockIdx.x, h = blockIdx.y, b = blockIdx.z;
    const int t = threadIdx.x;
    const int w = t >> 6, l = t & 63;
    const int lm = l & 15, lq = l >> 4;

    // stage Q once
#pragma unroll
    for (int i = 0; i < 2; ++i) {
        int ch = t + i * 256;
        int r = ch >> 3, c8 = ch & 7;
        *(uint4*)&Qs[r * QSTR + c8 * 8] =
            *(const uint4*)&qb[((size_t)(b * SEQ + qt * 64 + r)) * DMODEL + h * DHEAD + c8 * 8];
    }

    f32x4 O[4];
#pragma unroll
    for (int n0 = 0; n0 < 4; ++n0)
#pragma unroll
        for (int e = 0; e < 4; ++e) O[n0][e] = 0.f;
    float mrow[4] = {-3.4e38f, -3.4e38f, -3.4e38f, -3.4e38f};
    float lrow[4] = {0.f, 0.f, 0.f, 0.f};

    const int qrow = w * 16 + lm;              // A-operand row (QK and PV)
    const int prow = w * 16 + lq * 4;          // C-layout row base

    for (int kt = 0; kt < SEQ / 64; ++kt) {
        // stage K [key][d] and V^T [d][key]
#pragma unroll
        for (int i = 0; i < 2; ++i) {
            int ch = t + i * 256;
            int r = ch >> 3, c8 = ch & 7;
            *(uint4*)&Ks[r * QSTR + c8 * 8] =
                *(const uint4*)&kb[((size_t)(b * SEQ + kt * 64 + r)) * DMODEL + h * DHEAD + c8 * 8];
            *(uint4*)&Vs[r * QSTR + c8 * 8] =
                *(const uint4*)&vtb[(((size_t)(b * NHEAD + h)) * DHEAD + r) * SEQ + kt * 64 + c8 * 8];
        }
        if (t < 64) Ma[t] = (mask[b * SEQ + kt * 64 + t] == 0) ? -1e9f : 0.f;
        __syncthreads();

        // QK^T
        bf16x8 aq0 = *(const bf16x8*)&Qs[qrow * QSTR + lq * 8];
        bf16x8 aq1 = *(const bf16x8*)&Qs[qrow * QSTR + lq * 8 + 32];
        f32x4 S[4];
#pragma unroll
        for (int n0 = 0; n0 < 4; ++n0) {
#pragma unroll
            for (int e = 0; e < 4; ++e) S[n0][e] = 0.f;
            bf16x8 b0 = *(const bf16x8*)&Ks[(n0 * 16 + lm) * QSTR + lq * 8];
            bf16x8 b1 = *(const bf16x8*)&Ks[(n0 * 16 + lm) * QSTR + lq * 8 + 32];
            S[n0] = __builtin_amdgcn_mfma_f32_16x16x32_bf16(aq0, b0, S[n0], 0, 0, 0);
            S[n0] = __builtin_amdgcn_mfma_f32_16x16x32_bf16(aq1, b1, S[n0], 0, 0, 0);
        }

        // online softmax (rows = prow+r, cols = n0*16+lm)
        float ma4[4];
#pragma unroll
        for (int n0 = 0; n0 < 4; ++n0) ma4[n0] = Ma[n0 * 16 + lm];
#pragma unroll
        for (int n0 = 0; n0 < 4; ++n0)
#pragma unroll
            for (int r = 0; r < 4; ++r) S[n0][r] += ma4[n0];

        float tm[4];
#pragma unroll
        for (int r = 0; r < 4; ++r)
            tm[r] = fmaxf(fmaxf(S[0][r], S[1][r]), fmaxf(S[2][r], S[3][r]));
#pragma unroll
        for (int off = 1; off < 16; off <<= 1)
#pragma unroll
            for (int r = 0; r < 4; ++r)
                tm[r] = fmaxf(tm[r], __shfl_xor(tm[r], off, 64));

        float al[4], ts[4];
#pragma unroll
        for (int r = 0; r < 4; ++r) {
            float mn = fmaxf(mrow[r], tm[r]);
            al[r] = __expf(mrow[r] - mn);
            mrow[r] = mn;
            ts[r] = 0.f;
        }
#pragma unroll
        for (int n0 = 0; n0 < 4; ++n0)
#pragma unroll
            for (int r = 0; r < 4; ++r) {
                float p = __expf(S[n0][r] - mrow[r]);
                ts[r] += p;
                Ps[(prow + r) * QSTR + n0 * 16 + lm] = f2b(p);
            }
#pragma unroll
        for (int off = 1; off < 16; off <<= 1)
#pragma unroll
            for (int r = 0; r < 4; ++r)
                ts[r] += __shfl_xor(ts[r], off, 64);
#pragma unroll
        for (int r = 0; r < 4; ++r) lrow[r] = lrow[r] * al[r] + ts[r];
#pragma unroll
        for (int n0 = 0; n0 < 4; ++n0)
#pragma unroll
            for (int r = 0; r < 4; ++r) O[n0][r] *= al[r];

        // PV (Ps rows wave-private -> no barrier; lgkmcnt ordering suffices)
        bf16x8 ap0 = *(const bf16x8*)&Ps[qrow * QSTR + lq * 8];
        bf16x8 ap1 = *(const bf16x8*)&Ps[qrow * QSTR + lq * 8 + 32];
#pragma unroll
        for (int n0 = 0; n0 < 4; ++n0) {
            bf16x8 v0 = *(const bf16x8*)&Vs[(n0 * 16 + lm) * QSTR + lq * 8];
            bf16x8 v1 = *(const bf16x8*)&Vs[(n0 * 16 + lm) * QSTR + lq * 8 + 32];
            O[n0] = __builtin_amdgcn_mfma_f32_16x16x32_bf16(ap0, v0, O[n0], 0, 0, 0);
            O[n0] = __builtin_amdgcn_mfma_f32_16x16x32_bf16(ap1, v1, O[n0], 0, 0, 0);
        }
        __syncthreads();   // tiles consumed before next stage
    }

    // normalize + coalesced store via LDS bounce (reuse Ks)
    float inv[4];
#pragma unroll
    for (int r = 0; r < 4; ++r) inv[r] = 1.f / lrow[r];
#pragma unroll
    for (int n0 = 0; n0 < 4; ++n0)
#pragma unroll
        for (int r = 0; r < 4; ++r)
            Ks[(prow + r) * QSTR + n0 * 16 + lm] = f2b(O[n0][r] * inv[r]);
    __syncthreads();
#pragma unroll
    for (int i = 0; i < 2; ++i) {
        int ch = t + i * 256;
        int r = ch >> 3, c8 = ch & 7;
        *(uint4*)&ctxb[((size_t)(b * SEQ + qt * 64 + r)) * DMODEL + h * DHEAD + c8 * 8] =
            *(const uint4*)&Ks[r * QSTR + c8 * 8];
    }
}

// ---------------------------------------------------------------------------
// Per-layer weight transpose+convert: K x N fp32 -> N x K bf16.
// ---------------------------------------------------------------------------
__global__ __launch_bounds__(256) void transpose_w(
    const float* __restrict__ Wq, const float* __restrict__ Wk,
    const float* __restrict__ Wv, const float* __restrict__ Wo,
    const float* __restrict__ W1, const float* __restrict__ W2,
    ushort* __restrict__ Wqt, ushort* __restrict__ Wkt,
    ushort* __restrict__ Wvt, ushort* __restrict__ Wot,
    ushort* __restrict__ W1t, ushort* __restrict__ W2t)
{
    __shared__ float tile[32][33];
    const int bid = blockIdx.x;
    const float* src; ushort* dst; int K, N, tx, ty;
    if (bid < 2304) {
        int m = bid / 576, tl = bid % 576;
        src = (m == 0) ? Wq : (m == 1) ? Wk : (m == 2) ? Wv : Wo;
        dst = (m == 0) ? Wqt : (m == 1) ? Wkt : (m == 2) ? Wvt : Wot;
        K = 768; N = 768; tx = tl % 24; ty = tl / 24;
    } else if (bid < 4608) {
        int tl = bid - 2304;
        src = W1; dst = W1t; K = 768; N = 3072; tx = tl % 96; ty = tl / 96;
    } else {
        int tl = bid - 4608;
        src = W2; dst = W2t; K = 3072; N = 768; tx = tl % 24; ty = tl / 24;
    }
    const int t = threadIdx.x;
    const int lx = t & 31, ly = t >> 5;
    const int n0 = tx * 32, k0 = ty * 32;
#pragma unroll
    for (int i = 0; i < 4; ++i)
        tile[lx][ly + i * 8] = src[(size_t)(k0 + ly + i * 8) * N + n0 + lx];
    __syncthreads();
#pragma unroll
    for (int i = 0; i < 4; ++i)
        ((bf16_t*)dst)[(size_t)(n0 + ly + i * 8) * K + k0 + lx] =
            (bf16_t)tile[ly + i * 8][lx];
}

// ---------------------------------------------------------------------------
__global__ __launch_bounds__(256) void f2bf_kernel(
    const float* __restrict__ src, ushort* __restrict__ dst)
{
    const size_t i = ((size_t)blockIdx.x * 256 + threadIdx.x) * 4;
    float4 v = *(const float4*)(src + i);
    ushort4 o;
    o.x = f2b(v.x); o.y = f2b(v.y); o.z = f2b(v.z); o.w = f2b(v.w);
    *(ushort4*)(dst + i) = o;
}

// ---------------------------------------------------------------------------
// out = LayerNorm(a + b); writes fp32 (residual) and bf16 (next GEMM input)
// ---------------------------------------------------------------------------
__global__ __launch_bounds__(256) void add_ln_kernel(
    const float* __restrict__ a, const float* __restrict__ b,
    const float* __restrict__ gw, const float* __restrict__ bw,
    float* __restrict__ out, ushort* __restrict__ outb)
{
    const int row = blockIdx.x;
    const int t = threadIdx.x;
    __shared__ float red[8];

    const float* ar = a + (size_t)row * DMODEL;
    const float* br = b + (size_t)row * DMODEL;

    float vals[3];
    float s = 0.f;
#pragma unroll
    for (int i = 0; i < 3; ++i) {
        vals[i] = ar[t + i * 256] + br[t + i * 256];
        s += vals[i];
    }
#pragma unroll
    for (int off = 32; off > 0; off >>= 1) s += __shfl_down(s, off, 64);
    if ((t & 63) == 0) red[t >> 6] = s;
    __syncthreads();
    const float mu = (red[0] + red[1] + red[2] + red[3]) * (1.0f / DMODEL);

    float vs = 0.f;
#pragma unroll
    for (int i = 0; i < 3; ++i) {
        float d = vals[i] - mu;
        vs += d * d;
    }
#pragma unroll
    for (int off = 32; off > 0; off >>= 1) vs += __shfl_down(vs, off, 64);
    if ((t & 63) == 0) red[4 + (t >> 6)] = vs;
    __syncthreads();
    const float var = (red[4] + red[5] + red[6] + red[7]) * (1.0f / DMODEL);
    const float inv = rsqrtf(var + 1e-12f);

#pragma unroll
    for (int i = 0; i < 3; ++i) {
        int c = t + i * 256;
        float v = (vals[i] - mu) * inv * gw[c] + bw[c];
        out[(size_t)row * DMODEL + c] = v;
        ((bf16_t*)outb)[(size_t)row * DMODEL + c] = (bf16_t)v;
    }
}

// ---------------------------------------------------------------------------
extern "C" void kernel_launch(void* const* d_in, const int* in_sizes, int n_in,
                              void* d_out, int out_size, void* d_ws, size_t ws_size,
                              hipStream_t stream)
{
    const float* x    = (const float*)d_in[0];
    const int*   mask = (const int*)d_in[1];
    const float* Wq = (const float*)d_in[2];
    const float* bq = (const float*)d_in[3];
    const float* Wk = (const float*)d_in[4];
    const float* bk = (const float*)d_in[5];
    const float* Wv = (const float*)d_in[6];
    const float* bv = (const float*)d_in[7];
    const float* Wo = (const float*)d_in[8];
    const float* bo = (const float*)d_in[9];
    const float* ln1g = (const float*)d_in[10];
    const float* ln1b = (const float*)d_in[11];
    const float* W1 = (const float*)d_in[12];
    const float* b1 = (const float*)d_in[13];
    const float* W2 = (const float*)d_in[14];
    const float* b2 = (const float*)d_in[15];
    const float* ln2g = (const float*)d_in[16];
    const float* ln2b = (const float*)d_in[17];

    // ---- workspace layout (~102 MB) ----
    float* f32b = (float*)d_ws;
    float* hbuf = f32b;            // h residual (fp32)
    float* f1   = f32b + ND;       // sa / ffn_out (fp32)
    float* h2   = f32b + 2 * ND;   // h2 residual (fp32)
    ushort* ub  = (ushort*)(f32b + 3 * ND);
    ushort* qb  = ub;                          // q bf16 (scaled)
    ushort* kb  = ub + ND;                     // k bf16
    ushort* vtb = ub + 2 * ND;                 // v^T bf16 [b,h,d,s]
    ushort* hb  = ub + 3 * ND;                 // h bf16
    ushort* U   = ub + 4 * ND;                 // gelu-out bf16 (NTOK x FF)
    ushort* ctxb = U;                          // ctx bf16 (aliases U; disjoint lifetime)
    ushort* Wqkvt = U + (size_t)NTOK * FFDIM;  // 2304 x 768 contiguous
    ushort* Wot = Wqkvt + 3 * 768 * 768;
    ushort* W1t = Wot + 768 * 768;             // 3072 x 768
    ushort* W2t = W1t + (size_t)768 * 3072;    // 768 x 3072

    hipMemcpyAsync(hbuf, x, ND * sizeof(float), hipMemcpyDeviceToDevice, stream);
    f2bf_kernel<<<(int)(ND / 1024), 256, 0, stream>>>(x, hb);

    const dim3 gQKV(18, 32);   // N=2304
    const dim3 gD(6, 32);      // N=768
    const dim3 gFF(24, 32);    // N=3072
    const dim3 gA(SEQ / 64, NHEAD, BATCH);

    for (int l = 0; l < NLAYER; ++l) {
        const float* Wq_l = Wq + (size_t)l * DMODEL * DMODEL;
        const float* Wk_l = Wk + (size_t)l * DMODEL * DMODEL;
        const float* Wv_l = Wv + (size_t)l * DMODEL * DMODEL;
        const float* Wo_l = Wo + (size_t)l * DMODEL * DMODEL;
        const float* W1_l = W1 + (size_t)l * DMODEL * FFDIM;
        const float* W2_l = W2 + (size_t)l * FFDIM * DMODEL;

        transpose_w<<<6912, 256, 0, stream>>>(Wq_l, Wk_l, Wv_l, Wo_l, W1_l, W2_l,
                                              Wqkvt, Wqkvt + 768 * 768,
                                              Wqkvt + 2 * 768 * 768, Wot, W1t, W2t);

        gemm_qkv<<<gQKV, 256, 0, stream>>>(hb, Wqkvt,
                                           bq + (size_t)l * DMODEL,
                                           bk + (size_t)l * DMODEL,
                                           bv + (size_t)l * DMODEL,
                                           qb, kb, vtb);

        attn_mfma<<<gA, 256, 0, stream>>>(qb, kb, vtb, mask, ctxb);

        gemm_mfma<<<gD, 256, 0, stream>>>(ctxb, Wot, bo + (size_t)l * DMODEL,
                                          f1, nullptr, NTOK, DMODEL, DMODEL, 0);

        add_ln_kernel<<<NTOK, 256, 0, stream>>>(f1, hbuf, ln1g + (size_t)l * DMODEL,
                                                ln1b + (size_t)l * DMODEL, h2, hb);

        gemm_mfma<<<gFF, 256, 0, stream>>>(hb, W1t, b1 + (size_t)l * FFDIM,
                                           nullptr, U, NTOK, DMODEL, FFDIM, 1);
        gemm_mfma<<<gD, 256, 0, stream>>>(U, W2t, b2 + (size_t)l * DMODEL,
                                          f1, nullptr, NTOK, FFDIM, DMODEL, 0);

        float* hout = (l == NLAYER - 1) ? (float*)d_out : hbuf;
        add_ln_kernel<<<NTOK, 256, 0, stream>>>(f1, h2, ln2g + (size_t)l * DMODEL,
                                                ln2b + (size_t)l * DMODEL, hout, hb);
    }
}

// Round 6
// 1310.865 us; speedup vs baseline: 11.5980x; 1.1341x over previous
//
#include <hip/hip_runtime.h>
#include <math.h>

#define NLAYER 6
#define DMODEL 768
#define NHEAD 12
#define DHEAD 64
#define FFDIM 3072
#define SEQ 512
#define BATCH 8
#define NTOK (BATCH * SEQ) /* 4096 */
#define ND ((size_t)NTOK * DMODEL)

typedef __bf16 bf16_t;
typedef __bf16 bf16x8 __attribute__((ext_vector_type(8)));
typedef float f32x4 __attribute__((ext_vector_type(4)));

__device__ __forceinline__ float bf2f(ushort u) {
    return __uint_as_float(((unsigned int)u) << 16);
}
union BFU { __bf16 h; ushort u; };
__device__ __forceinline__ ushort f2b(float x) { BFU c; c.h = (__bf16)x; return c.u; }

#define GLDS(gp, lp) __builtin_amdgcn_global_load_lds( \
    (const __attribute__((address_space(1))) void*)(gp), \
    (__attribute__((address_space(3))) void*)(lp), 16, 0, 0)

// ---------------------------------------------------------------------------
// bf16 MFMA GEMM (m97 structure): C = act(A @ B + bias)
// A: M x K bf16 row-major.  Bt: N x K bf16 row-major.
// 128x128 tile, BK=32, 256 threads (4 waves), wave = 64x64 via 4x4 MFMAs.
// act: 0 none, 1 exact gelu.  Writes Cf (fp32) or Cb (bf16).
// ---------------------------------------------------------------------------
__global__ __launch_bounds__(256) void gemm_mfma(
    const ushort* __restrict__ A, const ushort* __restrict__ Bt,
    const float* __restrict__ bias, float* __restrict__ Cf,
    ushort* __restrict__ Cb, int M, int K, int N, int act)
{
    __shared__ __align__(16) ushort As[4096];
    __shared__ __align__(16) ushort Bs[4096];

    const int t = threadIdx.x;
    const int w = t >> 6, l = t & 63;
    const int wr = w >> 1, wc = w & 1;
    const int row0 = blockIdx.y * 128, col0 = blockIdx.x * 128;

    f32x4 acc[4][4];
#pragma unroll
    for (int mi = 0; mi < 4; ++mi)
#pragma unroll
        for (int ni = 0; ni < 4; ++ni)
#pragma unroll
            for (int e = 0; e < 4; ++e) acc[mi][ni][e] = 0.f;

    const int c0 = t,       r0 = c0 >> 2, kg0 = (c0 & 3) ^ ((r0 >> 1) & 3);
    const int c1 = t + 256, r1 = c1 >> 2, kg1 = (c1 & 3) ^ ((r1 >> 1) & 3);
    const ushort* gA0 = A + (size_t)(row0 + r0) * K + kg0 * 8;
    const ushort* gA1 = A + (size_t)(row0 + r1) * K + kg1 * 8;
    const ushort* gB0 = Bt + (size_t)(col0 + r0) * K + kg0 * 8;
    const ushort* gB1 = Bt + (size_t)(col0 + r1) * K + kg1 * 8;
    ushort* lA0 = &As[w * 512];
    ushort* lA1 = &As[2048 + w * 512];
    ushort* lB0 = &Bs[w * 512];
    ushort* lB1 = &Bs[2048 + w * 512];

    const int lm = l & 15, lq = l >> 4;
    int aoff[4], boff[4];
#pragma unroll
    for (int mi = 0; mi < 4; ++mi) {
        int m = wr * 64 + mi * 16 + lm;
        aoff[mi] = m * 32 + (lq ^ ((m >> 1) & 3)) * 8;
    }
#pragma unroll
    for (int ni = 0; ni < 4; ++ni) {
        int n = wc * 64 + ni * 16 + lm;
        boff[ni] = n * 32 + (lq ^ ((n >> 1) & 3)) * 8;
    }

    for (int k0 = 0; k0 < K; k0 += 32) {
        GLDS(gA0 + k0, lA0);
        GLDS(gA1 + k0, lA1);
        GLDS(gB0 + k0, lB0);
        GLDS(gB1 + k0, lB1);
        __syncthreads();

        bf16x8 af[4], bfr[4];
#pragma unroll
        for (int mi = 0; mi < 4; ++mi) af[mi] = *(const bf16x8*)&As[aoff[mi]];
#pragma unroll
        for (int ni = 0; ni < 4; ++ni) bfr[ni] = *(const bf16x8*)&Bs[boff[ni]];

#pragma unroll
        for (int mi = 0; mi < 4; ++mi)
#pragma unroll
            for (int ni = 0; ni < 4; ++ni)
                acc[mi][ni] = __builtin_amdgcn_mfma_f32_16x16x32_bf16(
                    af[mi], bfr[ni], acc[mi][ni], 0, 0, 0);
        __syncthreads();
    }

#pragma unroll
    for (int mi = 0; mi < 4; ++mi) {
        int rowb = row0 + wr * 64 + mi * 16 + lq * 4;
#pragma unroll
        for (int ni = 0; ni < 4; ++ni) {
            int col = col0 + wc * 64 + ni * 16 + lm;
            float bv = bias[col];
#pragma unroll
            for (int r = 0; r < 4; ++r) {
                float v = acc[mi][ni][r] + bv;
                if (act == 1) v = 0.5f * v * (1.0f + erff(v * 0.70710678118654752f));
                size_t idx = (size_t)(rowb + r) * N + col;
                if (Cb) ((bf16_t*)Cb)[idx] = (bf16_t)v;
                else    Cf[idx] = v;
            }
        }
    }
}

// ---------------------------------------------------------------------------
// Split-K bf16 MFMA GEMM: blockIdx.z selects K-half and the EXPLICIT partial
// destination (P0 / P1 — fixed from round 5, where P+z*M*N clobbered h2).
// Bias folded into split 0.
// ---------------------------------------------------------------------------
__global__ __launch_bounds__(256) void gemm_mfma_sk(
    const ushort* __restrict__ A, const ushort* __restrict__ Bt,
    const float* __restrict__ bias, float* __restrict__ P0,
    float* __restrict__ P1, int M, int K, int N, int kLen)
{
    __shared__ __align__(16) ushort As[4096];
    __shared__ __align__(16) ushort Bs[4096];

    const int t = threadIdx.x;
    const int w = t >> 6, l = t & 63;
    const int wr = w >> 1, wc = w & 1;
    const int row0 = blockIdx.y * 128, col0 = blockIdx.x * 128;
    const int z = blockIdx.z;
    const int kOff = z * kLen;
    float* Pz = (z == 0) ? P0 : P1;

    f32x4 acc[4][4];
#pragma unroll
    for (int mi = 0; mi < 4; ++mi)
#pragma unroll
        for (int ni = 0; ni < 4; ++ni)
#pragma unroll
            for (int e = 0; e < 4; ++e) acc[mi][ni][e] = 0.f;

    const int c0 = t,       r0 = c0 >> 2, kg0 = (c0 & 3) ^ ((r0 >> 1) & 3);
    const int c1 = t + 256, r1 = c1 >> 2, kg1 = (c1 & 3) ^ ((r1 >> 1) & 3);
    const ushort* gA0 = A + (size_t)(row0 + r0) * K + kg0 * 8;
    const ushort* gA1 = A + (size_t)(row0 + r1) * K + kg1 * 8;
    const ushort* gB0 = Bt + (size_t)(col0 + r0) * K + kg0 * 8;
    const ushort* gB1 = Bt + (size_t)(col0 + r1) * K + kg1 * 8;
    ushort* lA0 = &As[w * 512];
    ushort* lA1 = &As[2048 + w * 512];
    ushort* lB0 = &Bs[w * 512];
    ushort* lB1 = &Bs[2048 + w * 512];

    const int lm = l & 15, lq = l >> 4;
    int aoff[4], boff[4];
#pragma unroll
    for (int mi = 0; mi < 4; ++mi) {
        int m = wr * 64 + mi * 16 + lm;
        aoff[mi] = m * 32 + (lq ^ ((m >> 1) & 3)) * 8;
    }
#pragma unroll
    for (int ni = 0; ni < 4; ++ni) {
        int n = wc * 64 + ni * 16 + lm;
        boff[ni] = n * 32 + (lq ^ ((n >> 1) & 3)) * 8;
    }

    for (int k0 = kOff; k0 < kOff + kLen; k0 += 32) {
        GLDS(gA0 + k0, lA0);
        GLDS(gA1 + k0, lA1);
        GLDS(gB0 + k0, lB0);
        GLDS(gB1 + k0, lB1);
        __syncthreads();

        bf16x8 af[4], bfr[4];
#pragma unroll
        for (int mi = 0; mi < 4; ++mi) af[mi] = *(const bf16x8*)&As[aoff[mi]];
#pragma unroll
        for (int ni = 0; ni < 4; ++ni) bfr[ni] = *(const bf16x8*)&Bs[boff[ni]];

#pragma unroll
        for (int mi = 0; mi < 4; ++mi)
#pragma unroll
            for (int ni = 0; ni < 4; ++ni)
                acc[mi][ni] = __builtin_amdgcn_mfma_f32_16x16x32_bf16(
                    af[mi], bfr[ni], acc[mi][ni], 0, 0, 0);
        __syncthreads();
    }

#pragma unroll
    for (int mi = 0; mi < 4; ++mi) {
        int rowb = row0 + wr * 64 + mi * 16 + lq * 4;
#pragma unroll
        for (int ni = 0; ni < 4; ++ni) {
            int col = col0 + wc * 64 + ni * 16 + lm;
            float bv = (z == 0) ? bias[col] : 0.f;
#pragma unroll
            for (int r = 0; r < 4; ++r)
                Pz[(size_t)(rowb + r) * N + col] = acc[mi][ni][r] + bv;
        }
    }
}

// ---------------------------------------------------------------------------
// Fused QKV GEMM: A (M x 768) @ Wqkvt^T (2304 x 768) -> q (scaled, token-major
// bf16), k (token-major bf16), v (TRANSPOSED [b,h,d,s] bf16 for attn PV).
// ---------------------------------------------------------------------------
__global__ __launch_bounds__(256) void gemm_qkv(
    const ushort* __restrict__ A, const ushort* __restrict__ Bt,
    const float* __restrict__ bq, const float* __restrict__ bk,
    const float* __restrict__ bv,
    ushort* __restrict__ qb, ushort* __restrict__ kb, ushort* __restrict__ vtb)
{
    __shared__ __align__(16) ushort As[4096];
    __shared__ __align__(16) ushort Bs[4096];

    const int K = DMODEL;
    const int t = threadIdx.x;
    const int w = t >> 6, l = t & 63;
    const int wr = w >> 1, wc = w & 1;
    const int row0 = blockIdx.y * 128, col0 = blockIdx.x * 128;
    const int seg = blockIdx.x / 6;            // 0=q 1=k 2=v

    f32x4 acc[4][4];
#pragma unroll
    for (int mi = 0; mi < 4; ++mi)
#pragma unroll
        for (int ni = 0; ni < 4; ++ni)
#pragma unroll
            for (int e = 0; e < 4; ++e) acc[mi][ni][e] = 0.f;

    const int c0 = t,       r0 = c0 >> 2, kg0 = (c0 & 3) ^ ((r0 >> 1) & 3);
    const int c1 = t + 256, r1 = c1 >> 2, kg1 = (c1 & 3) ^ ((r1 >> 1) & 3);
    const ushort* gA0 = A + (size_t)(row0 + r0) * K + kg0 * 8;
    const ushort* gA1 = A + (size_t)(row0 + r1) * K + kg1 * 8;
    const ushort* gB0 = Bt + (size_t)(col0 + r0) * K + kg0 * 8;
    const ushort* gB1 = Bt + (size_t)(col0 + r1) * K + kg1 * 8;
    ushort* lA0 = &As[w * 512];
    ushort* lA1 = &As[2048 + w * 512];
    ushort* lB0 = &Bs[w * 512];
    ushort* lB1 = &Bs[2048 + w * 512];

    const int lm = l & 15, lq = l >> 4;
    int aoff[4], boff[4];
#pragma unroll
    for (int mi = 0; mi < 4; ++mi) {
        int m = wr * 64 + mi * 16 + lm;
        aoff[mi] = m * 32 + (lq ^ ((m >> 1) & 3)) * 8;
    }
#pragma unroll
    for (int ni = 0; ni < 4; ++ni) {
        int n = wc * 64 + ni * 16 + lm;
        boff[ni] = n * 32 + (lq ^ ((n >> 1) & 3)) * 8;
    }

    for (int k0 = 0; k0 < K; k0 += 32) {
        GLDS(gA0 + k0, lA0);
        GLDS(gA1 + k0, lA1);
        GLDS(gB0 + k0, lB0);
        GLDS(gB1 + k0, lB1);
        __syncthreads();

        bf16x8 af[4], bfr[4];
#pragma unroll
        for (int mi = 0; mi < 4; ++mi) af[mi] = *(const bf16x8*)&As[aoff[mi]];
#pragma unroll
        for (int ni = 0; ni < 4; ++ni) bfr[ni] = *(const bf16x8*)&Bs[boff[ni]];

#pragma unroll
        for (int mi = 0; mi < 4; ++mi)
#pragma unroll
            for (int ni = 0; ni < 4; ++ni)
                acc[mi][ni] = __builtin_amdgcn_mfma_f32_16x16x32_bf16(
                    af[mi], bfr[ni], acc[mi][ni], 0, 0, 0);
        __syncthreads();
    }

    const float* bp = (seg == 0) ? bq : (seg == 1) ? bk : bv;
    const float sc = (seg == 0) ? 0.125f : 1.0f;
#pragma unroll
    for (int mi = 0; mi < 4; ++mi) {
        int rowb = row0 + wr * 64 + mi * 16 + lq * 4;
#pragma unroll
        for (int ni = 0; ni < 4; ++ni) {
            int col = col0 + wc * 64 + ni * 16 + lm;
            int lcol = col - seg * 768;
            float bvv = bp[lcol];
            if (seg == 2) {
                int hh = lcol >> 6, dd = lcol & 63;
                int bb = rowb >> 9, ss = rowb & 511;
                ushort4 o;
                o.x = f2b(acc[mi][ni][0] + bvv);
                o.y = f2b(acc[mi][ni][1] + bvv);
                o.z = f2b(acc[mi][ni][2] + bvv);
                o.w = f2b(acc[mi][ni][3] + bvv);
                *(ushort4*)&vtb[(((size_t)(bb * NHEAD + hh)) * DHEAD + dd) * SEQ + ss] = o;
            } else {
                ushort* dst = seg ? kb : qb;
#pragma unroll
                for (int r = 0; r < 4; ++r)
                    dst[(size_t)(rowb + r) * DMODEL + lcol] = f2b((acc[mi][ni][r] + bvv) * sc);
            }
        }
    }
}

// ---------------------------------------------------------------------------
// MFMA flash attention (unchanged).
// ---------------------------------------------------------------------------
#define QSTR 72

__global__ __launch_bounds__(256) void attn_mfma(
    const ushort* __restrict__ qb, const ushort* __restrict__ kb,
    const ushort* __restrict__ vtb, const int* __restrict__ mask,
    ushort* __restrict__ ctxb)
{
    __shared__ __align__(16) ushort Qs[64 * QSTR];
    __shared__ __align__(16) ushort Ks[64 * QSTR];
    __shared__ __align__(16) ushort Vs[64 * QSTR];
    __shared__ __align__(16) ushort Ps[64 * QSTR];
    __shared__ float Ma[64];

    const int qt = blockIdx.x, h = blockIdx.y, b = blockIdx.z;
    const int t = threadIdx.x;
    const int w = t >> 6, l = t & 63;
    const int lm = l & 15, lq = l >> 4;

#pragma unroll
    for (int i = 0; i < 2; ++i) {
        int ch = t + i * 256;
        int r = ch >> 3, c8 = ch & 7;
        *(uint4*)&Qs[r * QSTR + c8 * 8] =
            *(const uint4*)&qb[((size_t)(b * SEQ + qt * 64 + r)) * DMODEL + h * DHEAD + c8 * 8];
    }

    f32x4 O[4];
#pragma unroll
    for (int n0 = 0; n0 < 4; ++n0)
#pragma unroll
        for (int e = 0; e < 4; ++e) O[n0][e] = 0.f;
    float mrow[4] = {-3.4e38f, -3.4e38f, -3.4e38f, -3.4e38f};
    float lrow[4] = {0.f, 0.f, 0.f, 0.f};

    const int qrow = w * 16 + lm;
    const int prow = w * 16 + lq * 4;

    for (int kt = 0; kt < SEQ / 64; ++kt) {
#pragma unroll
        for (int i = 0; i < 2; ++i) {
            int ch = t + i * 256;
            int r = ch >> 3, c8 = ch & 7;
            *(uint4*)&Ks[r * QSTR + c8 * 8] =
                *(const uint4*)&kb[((size_t)(b * SEQ + kt * 64 + r)) * DMODEL + h * DHEAD + c8 * 8];
            *(uint4*)&Vs[r * QSTR + c8 * 8] =
                *(const uint4*)&vtb[(((size_t)(b * NHEAD + h)) * DHEAD + r) * SEQ + kt * 64 + c8 * 8];
        }
        if (t < 64) Ma[t] = (mask[b * SEQ + kt * 64 + t] == 0) ? -1e9f : 0.f;
        __syncthreads();

        bf16x8 aq0 = *(const bf16x8*)&Qs[qrow * QSTR + lq * 8];
        bf16x8 aq1 = *(const bf16x8*)&Qs[qrow * QSTR + lq * 8 + 32];
        f32x4 S[4];
#pragma unroll
        for (int n0 = 0; n0 < 4; ++n0) {
#pragma unroll
            for (int e = 0; e < 4; ++e) S[n0][e] = 0.f;
            bf16x8 b0 = *(const bf16x8*)&Ks[(n0 * 16 + lm) * QSTR + lq * 8];
            bf16x8 b1 = *(const bf16x8*)&Ks[(n0 * 16 + lm) * QSTR + lq * 8 + 32];
            S[n0] = __builtin_amdgcn_mfma_f32_16x16x32_bf16(aq0, b0, S[n0], 0, 0, 0);
            S[n0] = __builtin_amdgcn_mfma_f32_16x16x32_bf16(aq1, b1, S[n0], 0, 0, 0);
        }

        float ma4[4];
#pragma unroll
        for (int n0 = 0; n0 < 4; ++n0) ma4[n0] = Ma[n0 * 16 + lm];
#pragma unroll
        for (int n0 = 0; n0 < 4; ++n0)
#pragma unroll
            for (int r = 0; r < 4; ++r) S[n0][r] += ma4[n0];

        float tm[4];
#pragma unroll
        for (int r = 0; r < 4; ++r)
            tm[r] = fmaxf(fmaxf(S[0][r], S[1][r]), fmaxf(S[2][r], S[3][r]));
#pragma unroll
        for (int off = 1; off < 16; off <<= 1)
#pragma unroll
            for (int r = 0; r < 4; ++r)
                tm[r] = fmaxf(tm[r], __shfl_xor(tm[r], off, 64));

        float al[4], ts[4];
#pragma unroll
        for (int r = 0; r < 4; ++r) {
            float mn = fmaxf(mrow[r], tm[r]);
            al[r] = __expf(mrow[r] - mn);
            mrow[r] = mn;
            ts[r] = 0.f;
        }
#pragma unroll
        for (int n0 = 0; n0 < 4; ++n0)
#pragma unroll
            for (int r = 0; r < 4; ++r) {
                float p = __expf(S[n0][r] - mrow[r]);
                ts[r] += p;
                Ps[(prow + r) * QSTR + n0 * 16 + lm] = f2b(p);
            }
#pragma unroll
        for (int off = 1; off < 16; off <<= 1)
#pragma unroll
            for (int r = 0; r < 4; ++r)
                ts[r] += __shfl_xor(ts[r], off, 64);
#pragma unroll
        for (int r = 0; r < 4; ++r) lrow[r] = lrow[r] * al[r] + ts[r];
#pragma unroll
        for (int n0 = 0; n0 < 4; ++n0)
#pragma unroll
            for (int r = 0; r < 4; ++r) O[n0][r] *= al[r];

        bf16x8 ap0 = *(const bf16x8*)&Ps[qrow * QSTR + lq * 8];
        bf16x8 ap1 = *(const bf16x8*)&Ps[qrow * QSTR + lq * 8 + 32];
#pragma unroll
        for (int n0 = 0; n0 < 4; ++n0) {
            bf16x8 v0 = *(const bf16x8*)&Vs[(n0 * 16 + lm) * QSTR + lq * 8];
            bf16x8 v1 = *(const bf16x8*)&Vs[(n0 * 16 + lm) * QSTR + lq * 8 + 32];
            O[n0] = __builtin_amdgcn_mfma_f32_16x16x32_bf16(ap0, v0, O[n0], 0, 0, 0);
            O[n0] = __builtin_amdgcn_mfma_f32_16x16x32_bf16(ap1, v1, O[n0], 0, 0, 0);
        }
        __syncthreads();
    }

    float inv[4];
#pragma unroll
    for (int r = 0; r < 4; ++r) inv[r] = 1.f / lrow[r];
#pragma unroll
    for (int n0 = 0; n0 < 4; ++n0)
#pragma unroll
        for (int r = 0; r < 4; ++r)
            Ks[(prow + r) * QSTR + n0 * 16 + lm] = f2b(O[n0][r] * inv[r]);
    __syncthreads();
#pragma unroll
    for (int i = 0; i < 2; ++i) {
        int ch = t + i * 256;
        int r = ch >> 3, c8 = ch & 7;
        *(uint4*)&ctxb[((size_t)(b * SEQ + qt * 64 + r)) * DMODEL + h * DHEAD + c8 * 8] =
            *(const uint4*)&Ks[r * QSTR + c8 * 8];
    }
}

// ---------------------------------------------------------------------------
// Per-layer weight transpose+convert: K x N fp32 -> N x K bf16.
// ---------------------------------------------------------------------------
__global__ __launch_bounds__(256) void transpose_w(
    const float* __restrict__ Wq, const float* __restrict__ Wk,
    const float* __restrict__ Wv, const float* __restrict__ Wo,
    const float* __restrict__ W1, const float* __restrict__ W2,
    ushort* __restrict__ Wqt, ushort* __restrict__ Wkt,
    ushort* __restrict__ Wvt, ushort* __restrict__ Wot,
    ushort* __restrict__ W1t, ushort* __restrict__ W2t)
{
    __shared__ float tile[32][33];
    const int bid = blockIdx.x;
    const float* src; ushort* dst; int K, N, tx, ty;
    if (bid < 2304) {
        int m = bid / 576, tl = bid % 576;
        src = (m == 0) ? Wq : (m == 1) ? Wk : (m == 2) ? Wv : Wo;
        dst = (m == 0) ? Wqt : (m == 1) ? Wkt : (m == 2) ? Wvt : Wot;
        K = 768; N = 768; tx = tl % 24; ty = tl / 24;
    } else if (bid < 4608) {
        int tl = bid - 2304;
        src = W1; dst = W1t; K = 768; N = 3072; tx = tl % 96; ty = tl / 96;
    } else {
        int tl = bid - 4608;
        src = W2; dst = W2t; K = 3072; N = 768; tx = tl % 24; ty = tl / 24;
    }
    const int t = threadIdx.x;
    const int lx = t & 31, ly = t >> 5;
    const int n0 = tx * 32, k0 = ty * 32;
#pragma unroll
    for (int i = 0; i < 4; ++i)
        tile[lx][ly + i * 8] = src[(size_t)(k0 + ly + i * 8) * N + n0 + lx];
    __syncthreads();
#pragma unroll
    for (int i = 0; i < 4; ++i)
        ((bf16_t*)dst)[(size_t)(n0 + ly + i * 8) * K + k0 + lx] =
            (bf16_t)tile[ly + i * 8][lx];
}

// ---------------------------------------------------------------------------
__global__ __launch_bounds__(256) void f2bf_kernel(
    const float* __restrict__ src, ushort* __restrict__ dst)
{
    const size_t i = ((size_t)blockIdx.x * 256 + threadIdx.x) * 4;
    float4 v = *(const float4*)(src + i);
    ushort4 o;
    o.x = f2b(v.x); o.y = f2b(v.y); o.z = f2b(v.z); o.w = f2b(v.w);
    *(ushort4*)(dst + i) = o;
}

// ---------------------------------------------------------------------------
// out = LayerNorm(p0 + p1 + res); fp32 out + bf16 shadow.
// ---------------------------------------------------------------------------
__global__ __launch_bounds__(256) void add_ln3_kernel(
    const float* __restrict__ p0, const float* __restrict__ p1,
    const float* __restrict__ res,
    const float* __restrict__ gw, const float* __restrict__ bw,
    float* __restrict__ out, ushort* __restrict__ outb)
{
    const int row = blockIdx.x;
    const int t = threadIdx.x;
    __shared__ float red[8];

    const float* a0 = p0 + (size_t)row * DMODEL;
    const float* a1 = p1 + (size_t)row * DMODEL;
    const float* rr = res + (size_t)row * DMODEL;

    float vals[3];
    float s = 0.f;
#pragma unroll
    for (int i = 0; i < 3; ++i) {
        int c = t + i * 256;
        vals[i] = a0[c] + a1[c] + rr[c];
        s += vals[i];
    }
#pragma unroll
    for (int off = 32; off > 0; off >>= 1) s += __shfl_down(s, off, 64);
    if ((t & 63) == 0) red[t >> 6] = s;
    __syncthreads();
    const float mu = (red[0] + red[1] + red[2] + red[3]) * (1.0f / DMODEL);

    float vs = 0.f;
#pragma unroll
    for (int i = 0; i < 3; ++i) {
        float d = vals[i] - mu;
        vs += d * d;
    }
#pragma unroll
    for (int off = 32; off > 0; off >>= 1) vs += __shfl_down(vs, off, 64);
    if ((t & 63) == 0) red[4 + (t >> 6)] = vs;
    __syncthreads();
    const float var = (red[4] + red[5] + red[6] + red[7]) * (1.0f / DMODEL);
    const float inv = rsqrtf(var + 1e-12f);

#pragma unroll
    for (int i = 0; i < 3; ++i) {
        int c = t + i * 256;
        float v = (vals[i] - mu) * inv * gw[c] + bw[c];
        out[(size_t)row * DMODEL + c] = v;
        ((bf16_t*)outb)[(size_t)row * DMODEL + c] = (bf16_t)v;
    }
}

// ---------------------------------------------------------------------------
extern "C" void kernel_launch(void* const* d_in, const int* in_sizes, int n_in,
                              void* d_out, int out_size, void* d_ws, size_t ws_size,
                              hipStream_t stream)
{
    const float* x    = (const float*)d_in[0];
    const int*   mask = (const int*)d_in[1];
    const float* Wq = (const float*)d_in[2];
    const float* bq = (const float*)d_in[3];
    const float* Wk = (const float*)d_in[4];
    const float* bk = (const float*)d_in[5];
    const float* Wv = (const float*)d_in[6];
    const float* bv = (const float*)d_in[7];
    const float* Wo = (const float*)d_in[8];
    const float* bo = (const float*)d_in[9];
    const float* ln1g = (const float*)d_in[10];
    const float* ln1b = (const float*)d_in[11];
    const float* W1 = (const float*)d_in[12];
    const float* b1 = (const float*)d_in[13];
    const float* W2 = (const float*)d_in[14];
    const float* b2 = (const float*)d_in[15];
    const float* ln2g = (const float*)d_in[16];
    const float* ln2b = (const float*)d_in[17];

    // ---- workspace layout (~102 MB) ----
    float* f32b = (float*)d_ws;
    float* hbuf = f32b;            // h residual (fp32)
    float* f1   = f32b + ND;       // split-K partial 0
    float* h2   = f32b + 2 * ND;   // h2 residual (fp32)
    ushort* ub  = (ushort*)(f32b + 3 * ND);
    ushort* qb  = ub;                          // q bf16 (scaled)
    ushort* kb  = ub + ND;                     // k bf16
    ushort* vtb = ub + 2 * ND;                 // v^T bf16 [b,h,d,s]
    ushort* hb  = ub + 3 * ND;                 // h bf16
    ushort* U   = ub + 4 * ND;                 // gelu-out bf16 (NTOK x FF)
    ushort* ctxb = U;                          // ctx bf16 (aliases U; disjoint lifetime)
    ushort* Wqkvt = U + (size_t)NTOK * FFDIM;  // 2304 x 768 contiguous
    ushort* Wot = Wqkvt + 3 * 768 * 768;
    ushort* W1t = Wot + 768 * 768;             // 3072 x 768
    ushort* W2t = W1t + (size_t)768 * 3072;    // 768 x 3072

    // split-K partial 1: ND floats overlaying qb+kb (dead when sk-GEMMs run;
    // rewritten by the NEXT layer's gemm_qkv only after add_ln3 consumed p1)
    float* p1 = (float*)ub;

    hipMemcpyAsync(hbuf, x, ND * sizeof(float), hipMemcpyDeviceToDevice, stream);
    f2bf_kernel<<<(int)(ND / 1024), 256, 0, stream>>>(x, hb);

    const dim3 gQKV(18, 32);        // N=2304
    const dim3 gSK(6, 32, 2);       // N=768, split-K=2
    const dim3 gFF(24, 32);         // N=3072
    const dim3 gA(SEQ / 64, NHEAD, BATCH);

    for (int l = 0; l < NLAYER; ++l) {
        const float* Wq_l = Wq + (size_t)l * DMODEL * DMODEL;
        const float* Wk_l = Wk + (size_t)l * DMODEL * DMODEL;
        const float* Wv_l = Wv + (size_t)l * DMODEL * DMODEL;
        const float* Wo_l = Wo + (size_t)l * DMODEL * DMODEL;
        const float* W1_l = W1 + (size_t)l * DMODEL * FFDIM;
        const float* W2_l = W2 + (size_t)l * FFDIM * DMODEL;

        transpose_w<<<6912, 256, 0, stream>>>(Wq_l, Wk_l, Wv_l, Wo_l, W1_l, W2_l,
                                              Wqkvt, Wqkvt + 768 * 768,
                                              Wqkvt + 2 * 768 * 768, Wot, W1t, W2t);

        gemm_qkv<<<gQKV, 256, 0, stream>>>(hb, Wqkvt,
                                           bq + (size_t)l * DMODEL,
                                           bk + (size_t)l * DMODEL,
                                           bv + (size_t)l * DMODEL,
                                           qb, kb, vtb);

        attn_mfma<<<gA, 256, 0, stream>>>(qb, kb, vtb, mask, ctxb);

        // sa = ctx @ Wo + bo, split-K=2 -> partials f1 (z=0) and p1 (z=1)
        gemm_mfma_sk<<<gSK, 256, 0, stream>>>(ctxb, Wot, bo + (size_t)l * DMODEL,
                                              f1, p1, NTOK, DMODEL, DMODEL, DMODEL / 2);

        // h2 = LN(f1 + p1 + h)
        add_ln3_kernel<<<NTOK, 256, 0, stream>>>(f1, p1, hbuf,
                                                 ln1g + (size_t)l * DMODEL,
                                                 ln1b + (size_t)l * DMODEL, h2, hb);

        gemm_mfma<<<gFF, 256, 0, stream>>>(hb, W1t, b1 + (size_t)l * FFDIM,
                                           nullptr, U, NTOK, DMODEL, FFDIM, 1);

        // ffn_out = U @ W2 + b2, split-K=2
        gemm_mfma_sk<<<gSK, 256, 0, stream>>>(U, W2t, b2 + (size_t)l * DMODEL,
                                              f1, p1, NTOK, FFDIM, DMODEL, FFDIM / 2);

        // h = LN(f1 + p1 + h2); last layer -> d_out
        float* hout = (l == NLAYER - 1) ? (float*)d_out : hbuf;
        add_ln3_kernel<<<NTOK, 256, 0, stream>>>(f1, p1, h2,
                                                 ln2g + (size_t)l * DMODEL,
                                                 ln2b + (size_t)l * DMODEL, hout, hb);
    }
}